// Round 1
// baseline (1383.556 us; speedup 1.0000x reference)
//
#include <hip/hip_runtime.h>

#define NN 50000
#define NE 800000
#define D  64
#define NL 2

static __device__ __forceinline__ float bf2f(unsigned short u) {
    return __uint_as_float(((unsigned)u) << 16);
}
static __device__ __forceinline__ unsigned short f2bf(float x) {
    unsigned u = __float_as_uint(x);
    u += 0x7fff + ((u >> 16) & 1);   // RNE
    return (unsigned short)(u >> 16);
}

// ---------------- CSR build (edge_index is identical for both layers) ----------------

__global__ void k_deg(const int* __restrict__ ei, int* __restrict__ deg) {
    int e = blockIdx.x * 256 + threadIdx.x;
    if (e < NE) atomicAdd(&deg[ei[NE + e]], 1);
}

__global__ void k_scan(const int* __restrict__ deg, int* __restrict__ row_off,
                       int* __restrict__ cursor) {
    __shared__ int buf[1024];
    __shared__ int carry_s;
    if (threadIdx.x == 0) carry_s = 0;
    __syncthreads();
    for (int base = 0; base < NN; base += 1024) {
        int i = base + (int)threadIdx.x;
        int v = (i < NN) ? deg[i] : 0;
        buf[threadIdx.x] = v;
        __syncthreads();
        for (int offt = 1; offt < 1024; offt <<= 1) {
            int t = (threadIdx.x >= (unsigned)offt) ? buf[threadIdx.x - offt] : 0;
            __syncthreads();
            buf[threadIdx.x] += t;
            __syncthreads();
        }
        int inc = buf[threadIdx.x] + carry_s;   // inclusive prefix through i
        if (i < NN) {
            row_off[i + 1] = inc;
            cursor[i] = inc - v;                 // exclusive
            if (i == 0) row_off[0] = 0;
        }
        __syncthreads();
        if (threadIdx.x == 1023) carry_s = inc;
        __syncthreads();
    }
}

__global__ void k_scatter(const int* __restrict__ ei, int* __restrict__ cursor,
                          int2* __restrict__ csr) {
    int e = blockIdx.x * 256 + threadIdx.x;
    if (e < NE) {
        int dst = ei[NE + e];
        int pos = atomicAdd(&cursor[dst], 1);
        csr[pos] = make_int2(e, ei[e]);          // (edge id, src)
    }
}

// ---------------- per-layer kernels ----------------

// Qh/Kh/Vh = h @ WQ/WK/WV   (thread per row, weights in LDS)
__global__ __launch_bounds__(256) void k_qkv(const float* __restrict__ h,
        const float* __restrict__ Wq, const float* __restrict__ Wk,
        const float* __restrict__ Wv,
        float* __restrict__ Qh, float* __restrict__ Kh, float* __restrict__ Vh) {
    __shared__ float w[3 * 4096];
    for (int i = threadIdx.x; i < 3 * 4096; i += 256)
        w[i] = (i < 4096) ? Wq[i] : (i < 8192 ? Wk[i - 4096] : Wv[i - 8192]);
    __syncthreads();
    int r = blockIdx.x * 256 + threadIdx.x;
    if (r >= NN) return;
    float hr[64];
    const float4* hp = (const float4*)(h + (size_t)r * D);
#pragma unroll
    for (int i = 0; i < 16; i++) {
        float4 v = hp[i];
        hr[4*i] = v.x; hr[4*i+1] = v.y; hr[4*i+2] = v.z; hr[4*i+3] = v.w;
    }
    for (int m = 0; m < 3; m++) {
        const float* wm = w + m * 4096;
        float4 acc[16];
#pragma unroll
        for (int i = 0; i < 16; i++) acc[i] = make_float4(0.f, 0.f, 0.f, 0.f);
        for (int j = 0; j < 64; j++) {
            float hj = hr[j];
            const float4* wr = (const float4*)(wm + j * 64);
#pragma unroll
            for (int d = 0; d < 16; d++) {
                float4 ww = wr[d];
                acc[d].x += hj * ww.x; acc[d].y += hj * ww.y;
                acc[d].z += hj * ww.z; acc[d].w += hj * ww.w;
            }
        }
        float* outp = (m == 0 ? Qh : (m == 1 ? Kh : Vh)) + (size_t)r * D;
#pragma unroll
        for (int d = 0; d < 16; d++) ((float4*)outp)[d] = acc[d];
    }
}

// Eh = edge_attr @ WE, stored bf16 (halves HBM/ws cost; tolerance is ~1e-1)
__global__ __launch_bounds__(256) void k_eh(const float* __restrict__ ea,
        const float* __restrict__ We, unsigned short* __restrict__ Eh) {
    __shared__ float w[4096];
    for (int i = threadIdx.x; i < 4096; i += 256) w[i] = We[i];
    __syncthreads();
    int e = blockIdx.x * 256 + threadIdx.x;
    if (e >= NE) return;
    float ar[64];
    const float4* ap = (const float4*)(ea + (size_t)e * D);
#pragma unroll
    for (int i = 0; i < 16; i++) {
        float4 v = ap[i];
        ar[4*i] = v.x; ar[4*i+1] = v.y; ar[4*i+2] = v.z; ar[4*i+3] = v.w;
    }
    float4 acc[16];
#pragma unroll
    for (int i = 0; i < 16; i++) acc[i] = make_float4(0.f, 0.f, 0.f, 0.f);
    for (int j = 0; j < 64; j++) {
        float aj = ar[j];
        const float4* wr = (const float4*)(w + j * 64);
#pragma unroll
        for (int d = 0; d < 16; d++) {
            float4 ww = wr[d];
            acc[d].x += aj * ww.x; acc[d].y += aj * ww.y;
            acc[d].z += aj * ww.z; acc[d].w += aj * ww.w;
        }
    }
    ushort4* op = (ushort4*)(Eh + (size_t)e * D);
#pragma unroll
    for (int d = 0; d < 16; d++)
        op[d] = make_ushort4(f2bf(acc[d].x), f2bf(acc[d].y), f2bf(acc[d].z), f2bf(acc[d].w));
}

// node-parallel attention aggregation: 16 lanes per node, no float atomics.
// lane covers d = 4*lane .. 4*lane+3 ; head = lane>>2 (DH=16).
__global__ __launch_bounds__(256) void k_agg(const float* __restrict__ Qh,
        const float* __restrict__ Kh, const float* __restrict__ Vh,
        const unsigned short* __restrict__ Eh,
        const int* __restrict__ row_off, const int2* __restrict__ csr,
        float* __restrict__ h_attn) {
    int t = blockIdx.x * 256 + threadIdx.x;
    int node = t >> 4;
    int lane = t & 15;
    if (node >= NN) return;
    int beg = row_off[node], end = row_off[node + 1];
    float4 q = ((const float4*)(Qh + (size_t)node * D))[lane];
    float4 acc = make_float4(0.f, 0.f, 0.f, 0.f);
    float z = 0.f;
    for (int i = beg; i < end; i++) {
        int2 es = csr[i];
        int e = es.x, s = es.y;
        float4 k4 = ((const float4*)(Kh + (size_t)s * D))[lane];
        ushort4 eb = ((const ushort4*)(Eh + (size_t)e * D))[lane];
        float part = k4.x * q.x * bf2f(eb.x) + k4.y * q.y * bf2f(eb.y)
                   + k4.z * q.z * bf2f(eb.z) + k4.w * q.w * bf2f(eb.w);
        part += __shfl_xor(part, 1, 64);
        part += __shfl_xor(part, 2, 64);       // sum over the head's 16 dims
        float sv = part * 0.25f;               // / sqrt(DH)
        sv = fminf(5.f, fmaxf(-5.f, sv));
        float sc = __expf(sv);
        float4 v4 = ((const float4*)(Vh + (size_t)s * D))[lane];
        acc.x += sc * v4.x; acc.y += sc * v4.y;
        acc.z += sc * v4.z; acc.w += sc * v4.w;
        z += sc;
    }
    float inv = 1.f / (z + 1e-6f);
    ((float4*)(h_attn + (size_t)node * D))[lane] =
        make_float4(acc.x * inv, acc.y * inv, acc.z * inv, acc.w * inv);
}

// fused: t = h + h_attn@WO + bO ; h1 = LN1(t) ; z = relu(h1@W1+b1)@W2+b2 ; out = LN2(h1+z)
__global__ __launch_bounds__(256) void k_post(const float* __restrict__ h_in,
        const float* __restrict__ h_attn,
        const float* __restrict__ Wo, const float* __restrict__ bo,
        const float* __restrict__ g1, const float* __restrict__ be1,
        const float* __restrict__ W1, const float* __restrict__ b1,
        const float* __restrict__ W2, const float* __restrict__ b2,
        const float* __restrict__ g2, const float* __restrict__ be2,
        float* __restrict__ h_out) {
    __shared__ float wo_s[4096];
    __shared__ float w1_s[8192];
    __shared__ float w2_s[8192];
    for (int i = threadIdx.x; i < 4096; i += 256) wo_s[i] = Wo[i];
    for (int i = threadIdx.x; i < 8192; i += 256) { w1_s[i] = W1[i]; w2_s[i] = W2[i]; }
    __syncthreads();
    int r = blockIdx.x * 256 + threadIdx.x;
    if (r >= NN) return;

    float hv[64];   // h_attn, later h1
    float zz[64];   // accumulator
    const float4* ap = (const float4*)(h_attn + (size_t)r * D);
#pragma unroll
    for (int i = 0; i < 16; i++) {
        float4 v = ap[i];
        hv[4*i] = v.x; hv[4*i+1] = v.y; hv[4*i+2] = v.z; hv[4*i+3] = v.w;
    }
#pragma unroll
    for (int i = 0; i < 64; i++) zz[i] = 0.f;
    for (int j = 0; j < 64; j++) {
        float aj = hv[j];
        const float4* wr = (const float4*)(wo_s + j * 64);
#pragma unroll
        for (int d = 0; d < 16; d++) {
            float4 ww = wr[d];
            zz[4*d]   += aj * ww.x; zz[4*d+1] += aj * ww.y;
            zz[4*d+2] += aj * ww.z; zz[4*d+3] += aj * ww.w;
        }
    }
    const float4* hp  = (const float4*)(h_in + (size_t)r * D);
    const float4* bo4 = (const float4*)bo;
#pragma unroll
    for (int i = 0; i < 16; i++) {
        float4 hh = hp[i]; float4 bb = bo4[i];
        zz[4*i]   += hh.x + bb.x; zz[4*i+1] += hh.y + bb.y;
        zz[4*i+2] += hh.z + bb.z; zz[4*i+3] += hh.w + bb.w;
    }
    // LN1
    float mu = 0.f;
#pragma unroll
    for (int i = 0; i < 64; i++) mu += zz[i];
    mu *= (1.f / 64.f);
    float var = 0.f;
#pragma unroll
    for (int i = 0; i < 64; i++) { float c = zz[i] - mu; var += c * c; }
    var *= (1.f / 64.f);
    float rstd = rsqrtf(var + 1e-5f);
#pragma unroll
    for (int i = 0; i < 64; i++) hv[i] = (zz[i] - mu) * rstd * g1[i] + be1[i];

    // FFN: zz = b2 ; zz += relu(hv@W1+b1) @ W2
    const float4* b2v = (const float4*)b2;
#pragma unroll
    for (int i = 0; i < 16; i++) {
        float4 bb = b2v[i];
        zz[4*i] = bb.x; zz[4*i+1] = bb.y; zz[4*i+2] = bb.z; zz[4*i+3] = bb.w;
    }
    const float4* b1v = (const float4*)b1;
    for (int k4 = 0; k4 < 32; k4++) {
        float4 y = b1v[k4];
        for (int j = 0; j < 64; j++) {
            float hj = hv[j];
            float4 ww = ((const float4*)(w1_s + j * 128))[k4];
            y.x += hj * ww.x; y.y += hj * ww.y; y.z += hj * ww.z; y.w += hj * ww.w;
        }
        y.x = fmaxf(y.x, 0.f); y.y = fmaxf(y.y, 0.f);
        y.z = fmaxf(y.z, 0.f); y.w = fmaxf(y.w, 0.f);
        const float* w2r0 = w2_s + (k4 * 4 + 0) * 64;
        const float* w2r1 = w2_s + (k4 * 4 + 1) * 64;
        const float* w2r2 = w2_s + (k4 * 4 + 2) * 64;
        const float* w2r3 = w2_s + (k4 * 4 + 3) * 64;
#pragma unroll
        for (int d = 0; d < 16; d++) {
            float4 a0 = ((const float4*)w2r0)[d];
            float4 a1 = ((const float4*)w2r1)[d];
            float4 a2 = ((const float4*)w2r2)[d];
            float4 a3 = ((const float4*)w2r3)[d];
            zz[4*d]   += y.x * a0.x + y.y * a1.x + y.z * a2.x + y.w * a3.x;
            zz[4*d+1] += y.x * a0.y + y.y * a1.y + y.z * a2.y + y.w * a3.y;
            zz[4*d+2] += y.x * a0.z + y.y * a1.z + y.z * a2.z + y.w * a3.z;
            zz[4*d+3] += y.x * a0.w + y.y * a1.w + y.z * a2.w + y.w * a3.w;
        }
    }
    // residual + LN2
#pragma unroll
    for (int i = 0; i < 64; i++) zz[i] += hv[i];
    mu = 0.f;
#pragma unroll
    for (int i = 0; i < 64; i++) mu += zz[i];
    mu *= (1.f / 64.f);
    var = 0.f;
#pragma unroll
    for (int i = 0; i < 64; i++) { float c = zz[i] - mu; var += c * c; }
    var *= (1.f / 64.f);
    rstd = rsqrtf(var + 1e-5f);
    float4* outp = (float4*)(h_out + (size_t)r * D);
#pragma unroll
    for (int i = 0; i < 16; i++) {
        float4 o;
        o.x = (zz[4*i]   - mu) * rstd * g2[4*i]   + be2[4*i];
        o.y = (zz[4*i+1] - mu) * rstd * g2[4*i+1] + be2[4*i+1];
        o.z = (zz[4*i+2] - mu) * rstd * g2[4*i+2] + be2[4*i+2];
        o.w = (zz[4*i+3] - mu) * rstd * g2[4*i+3] + be2[4*i+3];
        outp[i] = o;
    }
}

// ---------------- launch ----------------

extern "C" void kernel_launch(void* const* d_in, const int* in_sizes, int n_in,
                              void* d_out, int out_size, void* d_ws, size_t ws_size,
                              hipStream_t stream) {
    const float* x   = (const float*)d_in[0];
    const float* ea  = (const float*)d_in[1];
    const int*   ei  = (const int*)d_in[2];
    const float* WQ  = (const float*)d_in[3];
    const float* WK  = (const float*)d_in[4];
    const float* WE  = (const float*)d_in[5];
    const float* WV  = (const float*)d_in[6];
    const float* WO  = (const float*)d_in[7];
    const float* bO  = (const float*)d_in[8];
    const float* g1  = (const float*)d_in[9];
    const float* be1 = (const float*)d_in[10];
    const float* W1  = (const float*)d_in[11];
    const float* b1  = (const float*)d_in[12];
    const float* W2  = (const float*)d_in[13];
    const float* b2  = (const float*)d_in[14];
    const float* g2  = (const float*)d_in[15];
    const float* be2 = (const float*)d_in[16];
    float* out = (float*)d_out;

    char* wsb = (char*)d_ws;
    size_t off = 0;
    auto alloc = [&](size_t bytes) {
        void* p = wsb + off;
        off += (bytes + 255) & ~(size_t)255;
        return p;
    };
    float* Qh            = (float*)alloc((size_t)NN * D * 4);
    float* Kh            = (float*)alloc((size_t)NN * D * 4);
    float* Vh            = (float*)alloc((size_t)NN * D * 4);
    float* hbuf          = (float*)alloc((size_t)NN * D * 4);
    float* hattn         = (float*)alloc((size_t)NN * D * 4);
    unsigned short* Eh   = (unsigned short*)alloc((size_t)NE * D * 2);
    int* row_off         = (int*)alloc((size_t)(NN + 1) * 4);
    int* cursor          = (int*)alloc((size_t)NN * 4);
    int* deg             = (int*)alloc((size_t)NN * 4);
    int2* csr            = (int2*)alloc((size_t)NE * 8);

    // CSR build (once per call; edge_index shared by both layers)
    hipMemsetAsync(deg, 0, (size_t)NN * 4, stream);
    k_deg<<<(NE + 255) / 256, 256, 0, stream>>>(ei, deg);
    k_scan<<<1, 1024, 0, stream>>>(deg, row_off, cursor);
    k_scatter<<<(NE + 255) / 256, 256, 0, stream>>>(ei, cursor, csr);

    for (int l = 0; l < NL; l++) {
        const float* hcur = (l == 0) ? x : hbuf;
        float* hnxt = (l == NL - 1) ? out : hbuf;
        k_qkv<<<(NN + 255) / 256, 256, 0, stream>>>(hcur, WQ + l * 4096, WK + l * 4096,
                                                    WV + l * 4096, Qh, Kh, Vh);
        k_eh<<<(NE + 255) / 256, 256, 0, stream>>>(ea, WE + l * 4096, Eh);
        k_agg<<<(NN * 16 + 255) / 256, 256, 0, stream>>>(Qh, Kh, Vh, Eh, row_off, csr, hattn);
        k_post<<<(NN + 255) / 256, 256, 0, stream>>>(hcur, hattn,
                WO + l * 4096, bO + l * 64, g1 + l * 64, be1 + l * 64,
                W1 + l * 8192, b1 + l * 128, W2 + l * 8192, b2 + l * 64,
                g2 + l * 64, be2 + l * 64, hnxt);
    }
}

// Round 2
// 1132.302 us; speedup vs baseline: 1.2219x; 1.2219x over previous
//
#include <hip/hip_runtime.h>

#define NN 50000
#define NE 800000
#define D  64
#define NL 2

typedef __bf16 bf16x8 __attribute__((ext_vector_type(8)));
typedef float  floatx4 __attribute__((ext_vector_type(4)));

static __device__ __forceinline__ float bf2f(unsigned short u) {
    return __uint_as_float(((unsigned)u) << 16);
}
static __device__ __forceinline__ unsigned short f2bf(float x) {
    unsigned u = __float_as_uint(x);
    u += 0x7fff + ((u >> 16) & 1);   // RNE
    return (unsigned short)(u >> 16);
}

// ---------------- CSR build (edge_index is identical for both layers) ----------------

__global__ void k_deg(const int* __restrict__ ei, int* __restrict__ deg) {
    int e = blockIdx.x * 256 + threadIdx.x;
    if (e < NE) atomicAdd(&deg[ei[NE + e]], 1);
}

__global__ void k_scan(const int* __restrict__ deg, int* __restrict__ row_off,
                       int* __restrict__ cursor) {
    __shared__ int buf[1024];
    __shared__ int carry_s;
    if (threadIdx.x == 0) carry_s = 0;
    __syncthreads();
    for (int base = 0; base < NN; base += 1024) {
        int i = base + (int)threadIdx.x;
        int v = (i < NN) ? deg[i] : 0;
        buf[threadIdx.x] = v;
        __syncthreads();
        for (int offt = 1; offt < 1024; offt <<= 1) {
            int t = (threadIdx.x >= (unsigned)offt) ? buf[threadIdx.x - offt] : 0;
            __syncthreads();
            buf[threadIdx.x] += t;
            __syncthreads();
        }
        int inc = buf[threadIdx.x] + carry_s;   // inclusive prefix through i
        if (i < NN) {
            row_off[i + 1] = inc;
            cursor[i] = inc - v;                 // exclusive
            if (i == 0) row_off[0] = 0;
        }
        __syncthreads();
        if (threadIdx.x == 1023) carry_s = inc;
        __syncthreads();
    }
}

__global__ void k_scatter(const int* __restrict__ ei, int* __restrict__ cursor,
                          int2* __restrict__ csr) {
    int e = blockIdx.x * 256 + threadIdx.x;
    if (e < NE) {
        int dst = ei[NE + e];
        int pos = atomicAdd(&cursor[dst], 1);
        csr[pos] = make_int2(e, ei[e]);          // (edge id, src)
    }
}

// ---------------- per-layer kernels ----------------

// Qh/Kh/Vh = h @ WQ/WK/WV   (thread per row, weights in LDS)
__global__ __launch_bounds__(256) void k_qkv(const float* __restrict__ h,
        const float* __restrict__ Wq, const float* __restrict__ Wk,
        const float* __restrict__ Wv,
        float* __restrict__ Qh, float* __restrict__ Kh, float* __restrict__ Vh) {
    __shared__ float w[3 * 4096];
    for (int i = threadIdx.x; i < 3 * 4096; i += 256)
        w[i] = (i < 4096) ? Wq[i] : (i < 8192 ? Wk[i - 4096] : Wv[i - 8192]);
    __syncthreads();
    int r = blockIdx.x * 256 + threadIdx.x;
    if (r >= NN) return;
    float hr[64];
    const float4* hp = (const float4*)(h + (size_t)r * D);
#pragma unroll
    for (int i = 0; i < 16; i++) {
        float4 v = hp[i];
        hr[4*i] = v.x; hr[4*i+1] = v.y; hr[4*i+2] = v.z; hr[4*i+3] = v.w;
    }
    for (int m = 0; m < 3; m++) {
        const float* wm = w + m * 4096;
        float4 acc[16];
#pragma unroll
        for (int i = 0; i < 16; i++) acc[i] = make_float4(0.f, 0.f, 0.f, 0.f);
        for (int j = 0; j < 64; j++) {
            float hj = hr[j];
            const float4* wr = (const float4*)(wm + j * 64);
#pragma unroll
            for (int d = 0; d < 16; d++) {
                float4 ww = wr[d];
                acc[d].x += hj * ww.x; acc[d].y += hj * ww.y;
                acc[d].z += hj * ww.z; acc[d].w += hj * ww.w;
            }
        }
        float* outp = (m == 0 ? Qh : (m == 1 ? Kh : Vh)) + (size_t)r * D;
#pragma unroll
        for (int d = 0; d < 16; d++) ((float4*)outp)[d] = acc[d];
    }
}

// Eh = edge_attr @ WE via MFMA (bf16 in, fp32 acc, bf16 out).
// Per wave-iteration: one 16-edge slab. D-tile orientation: m = dim (from WE^T,
// held in registers, wave-uniform), n = edge. Epilogue stages the 16x64 bf16
// tile through wave-private LDS so global stores are fully coalesced
// (fixes the 3x WRITE_SIZE amplification seen in round 1).
__global__ __launch_bounds__(256) void k_eh_mfma(const float* __restrict__ ea,
        const float* __restrict__ We, unsigned short* __restrict__ Eh) {
    __shared__ unsigned short st[4][16 * 72];   // stride 72 ushorts = 144B (16B-aligned rows)
    const int lane = threadIdx.x & 63;
    const int w    = threadIdx.x >> 6;
    const int ml   = lane & 15;
    const int quad = lane >> 4;

    // A fragments: afr[kt][mt][j] = WE[kt*32+quad*8+j][mt*16+ml]  (A[m=d][k])
    bf16x8 afr[2][4];
#pragma unroll
    for (int kt = 0; kt < 2; kt++)
#pragma unroll
        for (int mt = 0; mt < 4; mt++)
#pragma unroll
            for (int j = 0; j < 8; j++)
                afr[kt][mt][j] = (__bf16)We[(kt*32 + quad*8 + j)*64 + mt*16 + ml];

    const int wave = blockIdx.x * 4 + w;
    const int nw   = gridDim.x * 4;
    for (int tile = wave; tile < NE / 16; tile += nw) {
        const int e0 = tile * 16;
        // B fragment: b[j] = ea[e0+ml][kt*32+quad*8+j]  (B[k][n=edge])
        const float4* ar = (const float4*)(ea + (size_t)(e0 + ml) * D);
        floatx4 acc[4] = {};
#pragma unroll
        for (int kt = 0; kt < 2; kt++) {
            float4 f0 = ar[kt*8 + quad*2 + 0];
            float4 f1 = ar[kt*8 + quad*2 + 1];
            bf16x8 b;
            b[0] = (__bf16)f0.x; b[1] = (__bf16)f0.y; b[2] = (__bf16)f0.z; b[3] = (__bf16)f0.w;
            b[4] = (__bf16)f1.x; b[5] = (__bf16)f1.y; b[6] = (__bf16)f1.z; b[7] = (__bf16)f1.w;
#pragma unroll
            for (int mt = 0; mt < 4; mt++)
                acc[mt] = __builtin_amdgcn_mfma_f32_16x16x32_bf16(afr[kt][mt], b, acc[mt], 0, 0, 0);
        }
        // D: lane holds Eh[e0+ml][mt*16+quad*4+reg], reg=0..3 → pack ushort4, stage in LDS
#pragma unroll
        for (int mt = 0; mt < 4; mt++) {
            ushort4 u = make_ushort4(f2bf(acc[mt][0]), f2bf(acc[mt][1]),
                                     f2bf(acc[mt][2]), f2bf(acc[mt][3]));
            *(ushort4*)&st[w][ml*72 + mt*16 + quad*4] = u;
        }
        // read back coalesced: lane covers edge el=lane>>2, 32B chunk c=lane&3
        const int el = lane >> 2, c = lane & 3;
        uint4 r0 = *(const uint4*)&st[w][el*72 + c*16 + 0];
        uint4 r1 = *(const uint4*)&st[w][el*72 + c*16 + 8];
        uint4* gp = (uint4*)(Eh + (size_t)(e0 + el) * D + c*16);
        gp[0] = r0;
        gp[1] = r1;
    }
}

// node-parallel attention aggregation: 16 lanes per node, no float atomics.
// lane covers d = 4*lane .. 4*lane+3 ; head = lane>>2 (DH=16).
__global__ __launch_bounds__(256) void k_agg(const float* __restrict__ Qh,
        const float* __restrict__ Kh, const float* __restrict__ Vh,
        const unsigned short* __restrict__ Eh,
        const int* __restrict__ row_off, const int2* __restrict__ csr,
        float* __restrict__ h_attn) {
    int t = blockIdx.x * 256 + threadIdx.x;
    int node = t >> 4;
    int lane = t & 15;
    if (node >= NN) return;
    int beg = row_off[node], end = row_off[node + 1];
    float4 q = ((const float4*)(Qh + (size_t)node * D))[lane];
    float4 acc = make_float4(0.f, 0.f, 0.f, 0.f);
    float z = 0.f;
    for (int i = beg; i < end; i++) {
        int2 es = csr[i];
        int e = es.x, s = es.y;
        float4 k4 = ((const float4*)(Kh + (size_t)s * D))[lane];
        ushort4 eb = ((const ushort4*)(Eh + (size_t)e * D))[lane];
        float part = k4.x * q.x * bf2f(eb.x) + k4.y * q.y * bf2f(eb.y)
                   + k4.z * q.z * bf2f(eb.z) + k4.w * q.w * bf2f(eb.w);
        part += __shfl_xor(part, 1, 64);
        part += __shfl_xor(part, 2, 64);       // sum over the head's 16 dims
        float sv = part * 0.25f;               // / sqrt(DH)
        sv = fminf(5.f, fmaxf(-5.f, sv));
        float sc = __expf(sv);
        float4 v4 = ((const float4*)(Vh + (size_t)s * D))[lane];
        acc.x += sc * v4.x; acc.y += sc * v4.y;
        acc.z += sc * v4.z; acc.w += sc * v4.w;
        z += sc;
    }
    float inv = 1.f / (z + 1e-6f);
    ((float4*)(h_attn + (size_t)node * D))[lane] =
        make_float4(acc.x * inv, acc.y * inv, acc.z * inv, acc.w * inv);
}

// fused: t = h + h_attn@WO + bO ; h1 = LN1(t) ; z = relu(h1@W1+b1)@W2+b2 ; out = LN2(h1+z)
__global__ __launch_bounds__(256) void k_post(const float* __restrict__ h_in,
        const float* __restrict__ h_attn,
        const float* __restrict__ Wo, const float* __restrict__ bo,
        const float* __restrict__ g1, const float* __restrict__ be1,
        const float* __restrict__ W1, const float* __restrict__ b1,
        const float* __restrict__ W2, const float* __restrict__ b2,
        const float* __restrict__ g2, const float* __restrict__ be2,
        float* __restrict__ h_out) {
    __shared__ float wo_s[4096];
    __shared__ float w1_s[8192];
    __shared__ float w2_s[8192];
    for (int i = threadIdx.x; i < 4096; i += 256) wo_s[i] = Wo[i];
    for (int i = threadIdx.x; i < 8192; i += 256) { w1_s[i] = W1[i]; w2_s[i] = W2[i]; }
    __syncthreads();
    int r = blockIdx.x * 256 + threadIdx.x;
    if (r >= NN) return;

    float hv[64];   // h_attn, later h1
    float zz[64];   // accumulator
    const float4* ap = (const float4*)(h_attn + (size_t)r * D);
#pragma unroll
    for (int i = 0; i < 16; i++) {
        float4 v = ap[i];
        hv[4*i] = v.x; hv[4*i+1] = v.y; hv[4*i+2] = v.z; hv[4*i+3] = v.w;
    }
#pragma unroll
    for (int i = 0; i < 64; i++) zz[i] = 0.f;
    for (int j = 0; j < 64; j++) {
        float aj = hv[j];
        const float4* wr = (const float4*)(wo_s + j * 64);
#pragma unroll
        for (int d = 0; d < 16; d++) {
            float4 ww = wr[d];
            zz[4*d]   += aj * ww.x; zz[4*d+1] += aj * ww.y;
            zz[4*d+2] += aj * ww.z; zz[4*d+3] += aj * ww.w;
        }
    }
    const float4* hp  = (const float4*)(h_in + (size_t)r * D);
    const float4* bo4 = (const float4*)bo;
#pragma unroll
    for (int i = 0; i < 16; i++) {
        float4 hh = hp[i]; float4 bb = bo4[i];
        zz[4*i]   += hh.x + bb.x; zz[4*i+1] += hh.y + bb.y;
        zz[4*i+2] += hh.z + bb.z; zz[4*i+3] += hh.w + bb.w;
    }
    // LN1
    float mu = 0.f;
#pragma unroll
    for (int i = 0; i < 64; i++) mu += zz[i];
    mu *= (1.f / 64.f);
    float var = 0.f;
#pragma unroll
    for (int i = 0; i < 64; i++) { float c = zz[i] - mu; var += c * c; }
    var *= (1.f / 64.f);
    float rstd = rsqrtf(var + 1e-5f);
#pragma unroll
    for (int i = 0; i < 64; i++) hv[i] = (zz[i] - mu) * rstd * g1[i] + be1[i];

    // FFN: zz = b2 ; zz += relu(hv@W1+b1) @ W2
    const float4* b2v = (const float4*)b2;
#pragma unroll
    for (int i = 0; i < 16; i++) {
        float4 bb = b2v[i];
        zz[4*i] = bb.x; zz[4*i+1] = bb.y; zz[4*i+2] = bb.z; zz[4*i+3] = bb.w;
    }
    const float4* b1v = (const float4*)b1;
    for (int k4 = 0; k4 < 32; k4++) {
        float4 y = b1v[k4];
        for (int j = 0; j < 64; j++) {
            float hj = hv[j];
            float4 ww = ((const float4*)(w1_s + j * 128))[k4];
            y.x += hj * ww.x; y.y += hj * ww.y; y.z += hj * ww.z; y.w += hj * ww.w;
        }
        y.x = fmaxf(y.x, 0.f); y.y = fmaxf(y.y, 0.f);
        y.z = fmaxf(y.z, 0.f); y.w = fmaxf(y.w, 0.f);
        const float* w2r0 = w2_s + (k4 * 4 + 0) * 64;
        const float* w2r1 = w2_s + (k4 * 4 + 1) * 64;
        const float* w2r2 = w2_s + (k4 * 4 + 2) * 64;
        const float* w2r3 = w2_s + (k4 * 4 + 3) * 64;
#pragma unroll
        for (int d = 0; d < 16; d++) {
            float4 a0 = ((const float4*)w2r0)[d];
            float4 a1 = ((const float4*)w2r1)[d];
            float4 a2 = ((const float4*)w2r2)[d];
            float4 a3 = ((const float4*)w2r3)[d];
            zz[4*d]   += y.x * a0.x + y.y * a1.x + y.z * a2.x + y.w * a3.x;
            zz[4*d+1] += y.x * a0.y + y.y * a1.y + y.z * a2.y + y.w * a3.y;
            zz[4*d+2] += y.x * a0.z + y.y * a1.z + y.z * a2.z + y.w * a3.z;
            zz[4*d+3] += y.x * a0.w + y.y * a1.w + y.z * a2.w + y.w * a3.w;
        }
    }
    // residual + LN2
#pragma unroll
    for (int i = 0; i < 64; i++) zz[i] += hv[i];
    mu = 0.f;
#pragma unroll
    for (int i = 0; i < 64; i++) mu += zz[i];
    mu *= (1.f / 64.f);
    var = 0.f;
#pragma unroll
    for (int i = 0; i < 64; i++) { float c = zz[i] - mu; var += c * c; }
    var *= (1.f / 64.f);
    rstd = rsqrtf(var + 1e-5f);
    float4* outp = (float4*)(h_out + (size_t)r * D);
#pragma unroll
    for (int i = 0; i < 16; i++) {
        float4 o;
        o.x = (zz[4*i]   - mu) * rstd * g2[4*i]   + be2[4*i];
        o.y = (zz[4*i+1] - mu) * rstd * g2[4*i+1] + be2[4*i+1];
        o.z = (zz[4*i+2] - mu) * rstd * g2[4*i+2] + be2[4*i+2];
        o.w = (zz[4*i+3] - mu) * rstd * g2[4*i+3] + be2[4*i+3];
        outp[i] = o;
    }
}

// ---------------- launch ----------------

extern "C" void kernel_launch(void* const* d_in, const int* in_sizes, int n_in,
                              void* d_out, int out_size, void* d_ws, size_t ws_size,
                              hipStream_t stream) {
    const float* x   = (const float*)d_in[0];
    const float* ea  = (const float*)d_in[1];
    const int*   ei  = (const int*)d_in[2];
    const float* WQ  = (const float*)d_in[3];
    const float* WK  = (const float*)d_in[4];
    const float* WE  = (const float*)d_in[5];
    const float* WV  = (const float*)d_in[6];
    const float* WO  = (const float*)d_in[7];
    const float* bO  = (const float*)d_in[8];
    const float* g1  = (const float*)d_in[9];
    const float* be1 = (const float*)d_in[10];
    const float* W1  = (const float*)d_in[11];
    const float* b1  = (const float*)d_in[12];
    const float* W2  = (const float*)d_in[13];
    const float* b2  = (const float*)d_in[14];
    const float* g2  = (const float*)d_in[15];
    const float* be2 = (const float*)d_in[16];
    float* out = (float*)d_out;

    char* wsb = (char*)d_ws;
    size_t off = 0;
    auto alloc = [&](size_t bytes) {
        void* p = wsb + off;
        off += (bytes + 255) & ~(size_t)255;
        return p;
    };
    float* Qh            = (float*)alloc((size_t)NN * D * 4);
    float* Kh            = (float*)alloc((size_t)NN * D * 4);
    float* Vh            = (float*)alloc((size_t)NN * D * 4);
    float* hbuf          = (float*)alloc((size_t)NN * D * 4);
    float* hattn         = (float*)alloc((size_t)NN * D * 4);
    unsigned short* Eh   = (unsigned short*)alloc((size_t)NE * D * 2);
    int* row_off         = (int*)alloc((size_t)(NN + 1) * 4);
    int* cursor          = (int*)alloc((size_t)NN * 4);
    int* deg             = (int*)alloc((size_t)NN * 4);
    int2* csr            = (int2*)alloc((size_t)NE * 8);

    // CSR build (once per call; edge_index shared by both layers)
    hipMemsetAsync(deg, 0, (size_t)NN * 4, stream);
    k_deg<<<(NE + 255) / 256, 256, 0, stream>>>(ei, deg);
    k_scan<<<1, 1024, 0, stream>>>(deg, row_off, cursor);
    k_scatter<<<(NE + 255) / 256, 256, 0, stream>>>(ei, cursor, csr);

    for (int l = 0; l < NL; l++) {
        const float* hcur = (l == 0) ? x : hbuf;
        float* hnxt = (l == NL - 1) ? out : hbuf;
        k_qkv<<<(NN + 255) / 256, 256, 0, stream>>>(hcur, WQ + l * 4096, WK + l * 4096,
                                                    WV + l * 4096, Qh, Kh, Vh);
        k_eh_mfma<<<1024, 256, 0, stream>>>(ea, WE + l * 4096, Eh);
        k_agg<<<(NN * 16 + 255) / 256, 256, 0, stream>>>(Qh, Kh, Vh, Eh, row_off, csr, hattn);
        k_post<<<(NN + 255) / 256, 256, 0, stream>>>(hcur, hattn,
                WO + l * 4096, bO + l * 64, g1 + l * 64, be1 + l * 64,
                W1 + l * 8192, b1 + l * 128, W2 + l * 8192, b2 + l * 64,
                g2 + l * 64, be2 + l * 64, hnxt);
    }
}

// Round 3
// 889.189 us; speedup vs baseline: 1.5560x; 1.2734x over previous
//
#include <hip/hip_runtime.h>

#define NN 50000
#define NE 800000
#define D  64
#define NL 2

typedef __bf16 bf16x8 __attribute__((ext_vector_type(8)));
typedef float  floatx4 __attribute__((ext_vector_type(4)));

static __device__ __forceinline__ float bf2f(unsigned short u) {
    return __uint_as_float(((unsigned)u) << 16);
}
static __device__ __forceinline__ unsigned short f2bf(float x) {
    unsigned u = __float_as_uint(x);
    u += 0x7fff + ((u >> 16) & 1);   // RNE
    return (unsigned short)(u >> 16);
}

// ---------------- CSR build (edge_index is identical for both layers) ----------------

__global__ void k_deg(const int* __restrict__ ei, int* __restrict__ deg) {
    int e = blockIdx.x * 256 + threadIdx.x;
    if (e < NE) atomicAdd(&deg[ei[NE + e]], 1);
}

__global__ void k_scan(const int* __restrict__ deg, int* __restrict__ row_off,
                       int* __restrict__ cursor) {
    __shared__ int buf[1024];
    __shared__ int carry_s;
    if (threadIdx.x == 0) carry_s = 0;
    __syncthreads();
    for (int base = 0; base < NN; base += 1024) {
        int i = base + (int)threadIdx.x;
        int v = (i < NN) ? deg[i] : 0;
        buf[threadIdx.x] = v;
        __syncthreads();
        for (int offt = 1; offt < 1024; offt <<= 1) {
            int t = (threadIdx.x >= (unsigned)offt) ? buf[threadIdx.x - offt] : 0;
            __syncthreads();
            buf[threadIdx.x] += t;
            __syncthreads();
        }
        int inc = buf[threadIdx.x] + carry_s;   // inclusive prefix through i
        if (i < NN) {
            row_off[i + 1] = inc;
            cursor[i] = inc - v;                 // exclusive
            if (i == 0) row_off[0] = 0;
        }
        __syncthreads();
        if (threadIdx.x == 1023) carry_s = inc;
        __syncthreads();
    }
}

__global__ void k_scatter(const int* __restrict__ ei, int* __restrict__ cursor,
                          int2* __restrict__ csr) {
    int e = blockIdx.x * 256 + threadIdx.x;
    if (e < NE) {
        int dst = ei[NE + e];
        int pos = atomicAdd(&cursor[dst], 1);
        csr[pos] = make_int2(e, ei[e]);          // (edge id, src)
    }
}

// transpose WO/W1/W2 (both layers) to bf16 m-major [m][k] once per call
__global__ __launch_bounds__(256) void k_prep(const float* __restrict__ WO,
        const float* __restrict__ W1, const float* __restrict__ W2,
        unsigned short* __restrict__ woT, unsigned short* __restrict__ w1T,
        unsigned short* __restrict__ w2T) {
    int idx = blockIdx.x * 256 + threadIdx.x;
    if (idx >= 2 * 20480) return;
    int l = idx / 20480;
    int r = idx % 20480;
    if (r < 4096) {                    // WO: [64k][64m] -> woT[m][k]
        int m = r >> 6, k = r & 63;
        woT[l * 4096 + r] = f2bf(WO[l * 4096 + k * 64 + m]);
    } else if (r < 12288) {            // W1: [64k][128m] -> w1T[m][k]
        int r2 = r - 4096;
        int m = r2 >> 6, k = r2 & 63;
        w1T[l * 8192 + r2] = f2bf(W1[l * 8192 + k * 128 + m]);
    } else {                           // W2: [128k][64m] -> w2T[m][k]
        int r3 = r - 12288;
        int m = r3 >> 7, k = r3 & 127;
        w2T[l * 8192 + r3] = f2bf(W2[l * 8192 + k * 64 + m]);
    }
}

// ---------------- per-layer kernels ----------------

// Qh/Kh/Vh = h @ WQ/WK/WV   (thread per row, weights in LDS)
__global__ __launch_bounds__(256) void k_qkv(const float* __restrict__ h,
        const float* __restrict__ Wq, const float* __restrict__ Wk,
        const float* __restrict__ Wv,
        float* __restrict__ Qh, float* __restrict__ Kh, float* __restrict__ Vh) {
    __shared__ float w[3 * 4096];
    for (int i = threadIdx.x; i < 3 * 4096; i += 256)
        w[i] = (i < 4096) ? Wq[i] : (i < 8192 ? Wk[i - 4096] : Wv[i - 8192]);
    __syncthreads();
    int r = blockIdx.x * 256 + threadIdx.x;
    if (r >= NN) return;
    float hr[64];
    const float4* hp = (const float4*)(h + (size_t)r * D);
#pragma unroll
    for (int i = 0; i < 16; i++) {
        float4 v = hp[i];
        hr[4*i] = v.x; hr[4*i+1] = v.y; hr[4*i+2] = v.z; hr[4*i+3] = v.w;
    }
    for (int m = 0; m < 3; m++) {
        const float* wm = w + m * 4096;
        float4 acc[16];
#pragma unroll
        for (int i = 0; i < 16; i++) acc[i] = make_float4(0.f, 0.f, 0.f, 0.f);
        for (int j = 0; j < 64; j++) {
            float hj = hr[j];
            const float4* wr = (const float4*)(wm + j * 64);
#pragma unroll
            for (int d = 0; d < 16; d++) {
                float4 ww = wr[d];
                acc[d].x += hj * ww.x; acc[d].y += hj * ww.y;
                acc[d].z += hj * ww.z; acc[d].w += hj * ww.w;
            }
        }
        float* outp = (m == 0 ? Qh : (m == 1 ? Kh : Vh)) + (size_t)r * D;
#pragma unroll
        for (int d = 0; d < 16; d++) ((float4*)outp)[d] = acc[d];
    }
}

// Eh = edge_attr @ WE via MFMA (bf16 in, fp32 acc, bf16 out).
__global__ __launch_bounds__(256) void k_eh_mfma(const float* __restrict__ ea,
        const float* __restrict__ We, unsigned short* __restrict__ Eh) {
    __shared__ unsigned short st[4][16 * 72];
    const int lane = threadIdx.x & 63;
    const int w    = threadIdx.x >> 6;
    const int ml   = lane & 15;
    const int quad = lane >> 4;

    bf16x8 afr[2][4];
#pragma unroll
    for (int kt = 0; kt < 2; kt++)
#pragma unroll
        for (int mt = 0; mt < 4; mt++)
#pragma unroll
            for (int j = 0; j < 8; j++)
                afr[kt][mt][j] = (__bf16)We[(kt*32 + quad*8 + j)*64 + mt*16 + ml];

    const int wave = blockIdx.x * 4 + w;
    const int nw   = gridDim.x * 4;
    for (int tile = wave; tile < NE / 16; tile += nw) {
        const int e0 = tile * 16;
        const float4* ar = (const float4*)(ea + (size_t)(e0 + ml) * D);
        floatx4 acc[4] = {};
#pragma unroll
        for (int kt = 0; kt < 2; kt++) {
            float4 f0 = ar[kt*8 + quad*2 + 0];
            float4 f1 = ar[kt*8 + quad*2 + 1];
            bf16x8 b;
            b[0] = (__bf16)f0.x; b[1] = (__bf16)f0.y; b[2] = (__bf16)f0.z; b[3] = (__bf16)f0.w;
            b[4] = (__bf16)f1.x; b[5] = (__bf16)f1.y; b[6] = (__bf16)f1.z; b[7] = (__bf16)f1.w;
#pragma unroll
            for (int mt = 0; mt < 4; mt++)
                acc[mt] = __builtin_amdgcn_mfma_f32_16x16x32_bf16(afr[kt][mt], b, acc[mt], 0, 0, 0);
        }
#pragma unroll
        for (int mt = 0; mt < 4; mt++) {
            ushort4 u = make_ushort4(f2bf(acc[mt][0]), f2bf(acc[mt][1]),
                                     f2bf(acc[mt][2]), f2bf(acc[mt][3]));
            *(ushort4*)&st[w][ml*72 + mt*16 + quad*4] = u;
        }
        const int el = lane >> 2, c = lane & 3;
        uint4 r0 = *(const uint4*)&st[w][el*72 + c*16 + 0];
        uint4 r1 = *(const uint4*)&st[w][el*72 + c*16 + 8];
        uint4* gp = (uint4*)(Eh + (size_t)(e0 + el) * D + c*16);
        gp[0] = r0;
        gp[1] = r1;
    }
}

// node-parallel attention aggregation: 16 lanes per node, no float atomics.
__global__ __launch_bounds__(256) void k_agg(const float* __restrict__ Qh,
        const float* __restrict__ Kh, const float* __restrict__ Vh,
        const unsigned short* __restrict__ Eh,
        const int* __restrict__ row_off, const int2* __restrict__ csr,
        float* __restrict__ h_attn) {
    int t = blockIdx.x * 256 + threadIdx.x;
    int node = t >> 4;
    int lane = t & 15;
    if (node >= NN) return;
    int beg = row_off[node], end = row_off[node + 1];
    float4 q = ((const float4*)(Qh + (size_t)node * D))[lane];
    float4 acc = make_float4(0.f, 0.f, 0.f, 0.f);
    float z = 0.f;
    for (int i = beg; i < end; i++) {
        int2 es = csr[i];
        int e = es.x, s = es.y;
        float4 k4 = ((const float4*)(Kh + (size_t)s * D))[lane];
        ushort4 eb = ((const ushort4*)(Eh + (size_t)e * D))[lane];
        float part = k4.x * q.x * bf2f(eb.x) + k4.y * q.y * bf2f(eb.y)
                   + k4.z * q.z * bf2f(eb.z) + k4.w * q.w * bf2f(eb.w);
        part += __shfl_xor(part, 1, 64);
        part += __shfl_xor(part, 2, 64);       // sum over the head's 16 dims
        float sv = part * 0.25f;               // / sqrt(DH)
        sv = fminf(5.f, fmaxf(-5.f, sv));
        float sc = __expf(sv);
        float4 v4 = ((const float4*)(Vh + (size_t)s * D))[lane];
        acc.x += sc * v4.x; acc.y += sc * v4.y;
        acc.z += sc * v4.z; acc.w += sc * v4.w;
        z += sc;
    }
    float inv = 1.f / (z + 1e-6f);
    ((float4*)(h_attn + (size_t)node * D))[lane] =
        make_float4(acc.x * inv, acc.y * inv, acc.z * inv, acc.w * inv);
}

// MFMA-based fused post block: one 16-node tile per wave.
// D-layout convention (16x16x32): lane=(ml=node, quad), reg r -> row dim = mt*16+quad*4+r.
// LN reductions: in-lane over mt,r then __shfl_xor 16/32 (quad bits).
// Layout round-trips (D-layout -> B-operand) via wave-private bf16 LDS staging.
__global__ __launch_bounds__(512) void k_post_mfma(const float* __restrict__ h_in,
        const float* __restrict__ h_attn,
        const unsigned short* __restrict__ woT_g,
        const unsigned short* __restrict__ w1T_g,
        const unsigned short* __restrict__ w2T_g,
        const float* __restrict__ bo,
        const float* __restrict__ g1, const float* __restrict__ be1,
        const float* __restrict__ b1, const float* __restrict__ b2,
        const float* __restrict__ g2, const float* __restrict__ be2,
        float* __restrict__ h_out) {
    // padded strides (72 / 136) keep ds_read_b128 at 2-way bank aliasing (free)
    __shared__ unsigned short woT_s[64 * 72];     //  9216 B
    __shared__ unsigned short w1T_s[128 * 72];    // 18432 B
    __shared__ unsigned short w2T_s[64 * 136];    // 17408 B
    __shared__ unsigned short stg[8][16 * 136];   // 34816 B   (total 79872 B)

    const int t = threadIdx.x;
    {   // cooperative weight load (already bf16, m-major from k_prep)
        const uint4* s0 = (const uint4*)woT_g;
        { int i = t; if (i < 512) { int row = i >> 3, c = i & 7;
              *(uint4*)&woT_s[row*72 + c*8] = s0[i]; } }
        const uint4* s1 = (const uint4*)w1T_g;
        for (int i = t; i < 1024; i += 512) {
            int row = i >> 3, c = i & 7;
            *(uint4*)&w1T_s[row*72 + c*8] = s1[i];
        }
        const uint4* s2 = (const uint4*)w2T_g;
        for (int i = t; i < 1024; i += 512) {
            int row = i >> 4, c = i & 15;
            *(uint4*)&w2T_s[row*136 + c*8] = s2[i];
        }
    }
    __syncthreads();

    const int w = t >> 6, lane = t & 63;
    const int ml = lane & 15, quad = lane >> 4;
    const int tile = blockIdx.x * 8 + w;
    if (tile >= NN / 16) return;
    const int e0 = tile * 16;
    unsigned short* st = stg[w];

    // ---- GEMM1: tt = h_attn @ WO  (B from global fp32, A from woT_s)
    const float4* ap = (const float4*)(h_attn + (size_t)(e0 + ml) * D);
    floatx4 acc1[4] = {};
#pragma unroll
    for (int kt = 0; kt < 2; kt++) {
        float4 f0 = ap[kt*8 + quad*2 + 0];
        float4 f1 = ap[kt*8 + quad*2 + 1];
        bf16x8 b;
        b[0] = (__bf16)f0.x; b[1] = (__bf16)f0.y; b[2] = (__bf16)f0.z; b[3] = (__bf16)f0.w;
        b[4] = (__bf16)f1.x; b[5] = (__bf16)f1.y; b[6] = (__bf16)f1.z; b[7] = (__bf16)f1.w;
#pragma unroll
        for (int mt = 0; mt < 4; mt++) {
            bf16x8 a = *(const bf16x8*)&woT_s[(mt*16 + ml)*72 + kt*32 + quad*8];
            acc1[mt] = __builtin_amdgcn_mfma_f32_16x16x32_bf16(a, b, acc1[mt], 0, 0, 0);
        }
    }
    // residual + bias, then LN1
    const float4* hp  = (const float4*)(h_in + (size_t)(e0 + ml) * D);
    const float4* bo4 = (const float4*)bo;
    floatx4 tt[4];
#pragma unroll
    for (int mt = 0; mt < 4; mt++) {
        float4 hh = hp[mt*4 + quad];
        float4 bb = bo4[mt*4 + quad];
        tt[mt][0] = acc1[mt][0] + hh.x + bb.x;
        tt[mt][1] = acc1[mt][1] + hh.y + bb.y;
        tt[mt][2] = acc1[mt][2] + hh.z + bb.z;
        tt[mt][3] = acc1[mt][3] + hh.w + bb.w;
    }
    float s = 0.f;
#pragma unroll
    for (int mt = 0; mt < 4; mt++) s += tt[mt][0] + tt[mt][1] + tt[mt][2] + tt[mt][3];
    s += __shfl_xor(s, 16, 64); s += __shfl_xor(s, 32, 64);
    float mu = s * (1.f / 64.f);
    float v = 0.f;
#pragma unroll
    for (int mt = 0; mt < 4; mt++)
#pragma unroll
        for (int r = 0; r < 4; r++) { float c = tt[mt][r] - mu; v += c * c; }
    v += __shfl_xor(v, 16, 64); v += __shfl_xor(v, 32, 64);
    float rstd = rsqrtf(v * (1.f / 64.f) + 1e-5f);
    const float4* g1v  = (const float4*)g1;
    const float4* be1v = (const float4*)be1;
    floatx4 h1[4];                    // h1 in D-layout (kept for residual)
#pragma unroll
    for (int mt = 0; mt < 4; mt++) {
        float4 gg = g1v[mt*4 + quad];
        float4 bb = be1v[mt*4 + quad];
        h1[mt][0] = (tt[mt][0] - mu) * rstd * gg.x + bb.x;
        h1[mt][1] = (tt[mt][1] - mu) * rstd * gg.y + bb.y;
        h1[mt][2] = (tt[mt][2] - mu) * rstd * gg.z + bb.z;
        h1[mt][3] = (tt[mt][3] - mu) * rstd * gg.w + bb.w;
        *(ushort4*)&st[ml*136 + mt*16 + quad*4] =
            make_ushort4(f2bf(h1[mt][0]), f2bf(h1[mt][1]), f2bf(h1[mt][2]), f2bf(h1[mt][3]));
    }

    // ---- GEMM2: y = relu(h1 @ W1 + b1), m = 0..127
    bf16x8 bh[2];
#pragma unroll
    for (int kt = 0; kt < 2; kt++)
        bh[kt] = *(const bf16x8*)&st[ml*136 + kt*32 + quad*8];
    floatx4 acc2[8] = {};
#pragma unroll
    for (int kt = 0; kt < 2; kt++)
#pragma unroll
        for (int mt = 0; mt < 8; mt++) {
            bf16x8 a = *(const bf16x8*)&w1T_s[(mt*16 + ml)*72 + kt*32 + quad*8];
            acc2[mt] = __builtin_amdgcn_mfma_f32_16x16x32_bf16(a, bh[kt], acc2[mt], 0, 0, 0);
        }
    const float4* b1v = (const float4*)b1;
#pragma unroll
    for (int mt = 0; mt < 8; mt++) {
        float4 bb = b1v[mt*4 + quad];
        float y0 = fmaxf(acc2[mt][0] + bb.x, 0.f);
        float y1 = fmaxf(acc2[mt][1] + bb.y, 0.f);
        float y2 = fmaxf(acc2[mt][2] + bb.z, 0.f);
        float y3 = fmaxf(acc2[mt][3] + bb.w, 0.f);
        *(ushort4*)&st[ml*136 + mt*16 + quad*4] =
            make_ushort4(f2bf(y0), f2bf(y1), f2bf(y2), f2bf(y3));
    }

    // ---- GEMM3: z = y @ W2, k = 0..127
    floatx4 acc3[4] = {};
#pragma unroll
    for (int kt = 0; kt < 4; kt++) {
        bf16x8 b = *(const bf16x8*)&st[ml*136 + kt*32 + quad*8];
#pragma unroll
        for (int mt = 0; mt < 4; mt++) {
            bf16x8 a = *(const bf16x8*)&w2T_s[(mt*16 + ml)*136 + kt*32 + quad*8];
            acc3[mt] = __builtin_amdgcn_mfma_f32_16x16x32_bf16(a, b, acc3[mt], 0, 0, 0);
        }
    }
    // + b2 + residual h1, LN2, scale, store
    const float4* b2v = (const float4*)b2;
#pragma unroll
    for (int mt = 0; mt < 4; mt++) {
        float4 bb = b2v[mt*4 + quad];
        tt[mt][0] = acc3[mt][0] + bb.x + h1[mt][0];
        tt[mt][1] = acc3[mt][1] + bb.y + h1[mt][1];
        tt[mt][2] = acc3[mt][2] + bb.z + h1[mt][2];
        tt[mt][3] = acc3[mt][3] + bb.w + h1[mt][3];
    }
    s = 0.f;
#pragma unroll
    for (int mt = 0; mt < 4; mt++) s += tt[mt][0] + tt[mt][1] + tt[mt][2] + tt[mt][3];
    s += __shfl_xor(s, 16, 64); s += __shfl_xor(s, 32, 64);
    mu = s * (1.f / 64.f);
    v = 0.f;
#pragma unroll
    for (int mt = 0; mt < 4; mt++)
#pragma unroll
        for (int r = 0; r < 4; r++) { float c = tt[mt][r] - mu; v += c * c; }
    v += __shfl_xor(v, 16, 64); v += __shfl_xor(v, 32, 64);
    rstd = rsqrtf(v * (1.f / 64.f) + 1e-5f);
    const float4* g2v  = (const float4*)g2;
    const float4* be2v = (const float4*)be2;
    float4* outp = (float4*)(h_out + (size_t)(e0 + ml) * D);
#pragma unroll
    for (int mt = 0; mt < 4; mt++) {
        float4 gg = g2v[mt*4 + quad];
        float4 bb = be2v[mt*4 + quad];
        float4 o;
        o.x = (tt[mt][0] - mu) * rstd * gg.x + bb.x;
        o.y = (tt[mt][1] - mu) * rstd * gg.y + bb.y;
        o.z = (tt[mt][2] - mu) * rstd * gg.z + bb.z;
        o.w = (tt[mt][3] - mu) * rstd * gg.w + bb.w;
        outp[mt*4 + quad] = o;
    }
}

// ---------------- launch ----------------

extern "C" void kernel_launch(void* const* d_in, const int* in_sizes, int n_in,
                              void* d_out, int out_size, void* d_ws, size_t ws_size,
                              hipStream_t stream) {
    const float* x   = (const float*)d_in[0];
    const float* ea  = (const float*)d_in[1];
    const int*   ei  = (const int*)d_in[2];
    const float* WQ  = (const float*)d_in[3];
    const float* WK  = (const float*)d_in[4];
    const float* WE  = (const float*)d_in[5];
    const float* WV  = (const float*)d_in[6];
    const float* WO  = (const float*)d_in[7];
    const float* bO  = (const float*)d_in[8];
    const float* g1  = (const float*)d_in[9];
    const float* be1 = (const float*)d_in[10];
    const float* W1  = (const float*)d_in[11];
    const float* b1  = (const float*)d_in[12];
    const float* W2  = (const float*)d_in[13];
    const float* b2  = (const float*)d_in[14];
    const float* g2  = (const float*)d_in[15];
    const float* be2 = (const float*)d_in[16];
    float* out = (float*)d_out;

    char* wsb = (char*)d_ws;
    size_t off = 0;
    auto alloc = [&](size_t bytes) {
        void* p = wsb + off;
        off += (bytes + 255) & ~(size_t)255;
        return p;
    };
    float* Qh            = (float*)alloc((size_t)NN * D * 4);
    float* Kh            = (float*)alloc((size_t)NN * D * 4);
    float* Vh            = (float*)alloc((size_t)NN * D * 4);
    float* hbuf          = (float*)alloc((size_t)NN * D * 4);
    float* hattn         = (float*)alloc((size_t)NN * D * 4);
    unsigned short* Eh   = (unsigned short*)alloc((size_t)NE * D * 2);
    int* row_off         = (int*)alloc((size_t)(NN + 1) * 4);
    int* cursor          = (int*)alloc((size_t)NN * 4);
    int* deg             = (int*)alloc((size_t)NN * 4);
    int2* csr            = (int2*)alloc((size_t)NE * 8);
    unsigned short* woT  = (unsigned short*)alloc((size_t)2 * 4096 * 2);
    unsigned short* w1T  = (unsigned short*)alloc((size_t)2 * 8192 * 2);
    unsigned short* w2T  = (unsigned short*)alloc((size_t)2 * 8192 * 2);

    // CSR build + weight prep (once per call)
    hipMemsetAsync(deg, 0, (size_t)NN * 4, stream);
    k_deg<<<(NE + 255) / 256, 256, 0, stream>>>(ei, deg);
    k_scan<<<1, 1024, 0, stream>>>(deg, row_off, cursor);
    k_scatter<<<(NE + 255) / 256, 256, 0, stream>>>(ei, cursor, csr);
    k_prep<<<(2 * 20480 + 255) / 256, 256, 0, stream>>>(WO, W1, W2, woT, w1T, w2T);

    for (int l = 0; l < NL; l++) {
        const float* hcur = (l == 0) ? x : hbuf;
        float* hnxt = (l == NL - 1) ? out : hbuf;
        k_qkv<<<(NN + 255) / 256, 256, 0, stream>>>(hcur, WQ + l * 4096, WK + l * 4096,
                                                    WV + l * 4096, Qh, Kh, Vh);
        k_eh_mfma<<<1024, 256, 0, stream>>>(ea, WE + l * 4096, Eh);
        k_agg<<<(NN * 16 + 255) / 256, 256, 0, stream>>>(Qh, Kh, Vh, Eh, row_off, csr, hattn);
        k_post_mfma<<<(NN / 16 + 7) / 8, 512, 0, stream>>>(hcur, hattn,
                woT + l * 4096, w1T + l * 8192, w2T + l * 8192,
                bO + l * 64, g1 + l * 64, be1 + l * 64,
                b1 + l * 128, b2 + l * 64,
                g2 + l * 64, be2 + l * 64, hnxt);
    }
}

// Round 4
// 746.906 us; speedup vs baseline: 1.8524x; 1.1905x over previous
//
#include <hip/hip_runtime.h>

#define NN 50000
#define NE 800000
#define D  64
#define NL 2

typedef __bf16 bf16x8 __attribute__((ext_vector_type(8)));
typedef float  floatx4 __attribute__((ext_vector_type(4)));

static __device__ __forceinline__ float bf2f(unsigned short u) {
    return __uint_as_float(((unsigned)u) << 16);
}
static __device__ __forceinline__ unsigned short f2bf(float x) {
    unsigned u = __float_as_uint(x);
    u += 0x7fff + ((u >> 16) & 1);   // RNE
    return (unsigned short)(u >> 16);
}

// ---------------- CSR build (edge_index is identical for both layers) ----------------

__global__ void k_deg(const int* __restrict__ ei, int* __restrict__ deg) {
    int e = blockIdx.x * 256 + threadIdx.x;
    if (e < NE) atomicAdd(&deg[ei[NE + e]], 1);
}

__global__ void k_scan(const int* __restrict__ deg, int* __restrict__ row_off,
                       int* __restrict__ cursor) {
    __shared__ int buf[1024];
    __shared__ int carry_s;
    if (threadIdx.x == 0) carry_s = 0;
    __syncthreads();
    for (int base = 0; base < NN; base += 1024) {
        int i = base + (int)threadIdx.x;
        int v = (i < NN) ? deg[i] : 0;
        buf[threadIdx.x] = v;
        __syncthreads();
        for (int offt = 1; offt < 1024; offt <<= 1) {
            int t = (threadIdx.x >= (unsigned)offt) ? buf[threadIdx.x - offt] : 0;
            __syncthreads();
            buf[threadIdx.x] += t;
            __syncthreads();
        }
        int inc = buf[threadIdx.x] + carry_s;   // inclusive prefix through i
        if (i < NN) {
            row_off[i + 1] = inc;
            cursor[i] = inc - v;                 // exclusive
            if (i == 0) row_off[0] = 0;
        }
        __syncthreads();
        if (threadIdx.x == 1023) carry_s = inc;
        __syncthreads();
    }
}

// csr_src[pos] = src ; eperm[e] = pos  (Eh gets written in CSR order)
__global__ void k_scatter(const int* __restrict__ ei, int* __restrict__ cursor,
                          int* __restrict__ csr_src, int* __restrict__ eperm) {
    int e = blockIdx.x * 256 + threadIdx.x;
    if (e < NE) {
        int dst = ei[NE + e];
        int pos = atomicAdd(&cursor[dst], 1);
        csr_src[pos] = ei[e];
        eperm[e] = pos;
    }
}

// transpose all weights to bf16 m-major [m][k] once per call.
// per-layer segments: wq,wk,wv,we (4096 each), wo (4096), w1 (8192), w2 (8192)
__global__ __launch_bounds__(256) void k_prep(
        const float* __restrict__ WQ, const float* __restrict__ WK,
        const float* __restrict__ WV, const float* __restrict__ WE,
        const float* __restrict__ WO, const float* __restrict__ W1,
        const float* __restrict__ W2,
        unsigned short* __restrict__ wqT, unsigned short* __restrict__ wkT,
        unsigned short* __restrict__ wvT, unsigned short* __restrict__ weT,
        unsigned short* __restrict__ woT, unsigned short* __restrict__ w1T,
        unsigned short* __restrict__ w2T) {
    int idx = blockIdx.x * 256 + threadIdx.x;
    if (idx >= 2 * 36864) return;
    int l = idx / 36864;
    int r = idx % 36864;
    if (r < 20480) {                       // five 64x64 matrices
        int which = r >> 12, rr = r & 4095;
        int m = rr >> 6, k = rr & 63;
        const float* src = (which == 0 ? WQ : which == 1 ? WK : which == 2 ? WV :
                            which == 3 ? WE : WO);
        unsigned short* dst = (which == 0 ? wqT : which == 1 ? wkT : which == 2 ? wvT :
                               which == 3 ? weT : woT);
        dst[l * 4096 + rr] = f2bf(src[l * 4096 + k * 64 + m]);
    } else if (r < 28672) {                // W1: [64k][128m] -> w1T[m][k]
        int r2 = r - 20480;
        int m = r2 >> 6, k = r2 & 63;
        w1T[l * 8192 + r2] = f2bf(W1[l * 8192 + k * 128 + m]);
    } else {                               // W2: [128k][64m] -> w2T[m][k]
        int r3 = r - 28672;
        int m = r3 >> 7, k = r3 & 127;
        w2T[l * 8192 + r3] = f2bf(W2[l * 8192 + k * 64 + m]);
    }
}

// ---------------- per-layer kernels ----------------

// QKV via MFMA: one 16-node tile per wave. Q stored fp32 (direct D-layout
// float4 stores = full 64B lines), K/V stored bf16 via LDS staging.
__global__ __launch_bounds__(256) void k_qkv_mfma(const float* __restrict__ h,
        const unsigned short* __restrict__ wqT, const unsigned short* __restrict__ wkT,
        const unsigned short* __restrict__ wvT,
        float* __restrict__ Qh, unsigned short* __restrict__ Kb,
        unsigned short* __restrict__ Vb) {
    __shared__ unsigned short st[4][16 * 72];
    const int lane = threadIdx.x & 63;
    const int w    = threadIdx.x >> 6;
    const int ml   = lane & 15;
    const int quad = lane >> 4;

    bf16x8 aq[2][4], ak[2][4], av[2][4];
#pragma unroll
    for (int kt = 0; kt < 2; kt++)
#pragma unroll
        for (int mt = 0; mt < 4; mt++) {
            int o = (mt*16 + ml)*64 + kt*32 + quad*8;
            aq[kt][mt] = *(const bf16x8*)&wqT[o];
            ak[kt][mt] = *(const bf16x8*)&wkT[o];
            av[kt][mt] = *(const bf16x8*)&wvT[o];
        }

    const int wave = blockIdx.x * 4 + w;
    const int nw   = gridDim.x * 4;
    for (int tile = wave; tile < NN / 16; tile += nw) {
        const int e0 = tile * 16;
        const float4* ar = (const float4*)(h + (size_t)(e0 + ml) * D);
        bf16x8 b[2];
#pragma unroll
        for (int kt = 0; kt < 2; kt++) {
            float4 f0 = ar[kt*8 + quad*2 + 0];
            float4 f1 = ar[kt*8 + quad*2 + 1];
            b[kt][0] = (__bf16)f0.x; b[kt][1] = (__bf16)f0.y;
            b[kt][2] = (__bf16)f0.z; b[kt][3] = (__bf16)f0.w;
            b[kt][4] = (__bf16)f1.x; b[kt][5] = (__bf16)f1.y;
            b[kt][6] = (__bf16)f1.z; b[kt][7] = (__bf16)f1.w;
        }
        floatx4 accq[4] = {}, acck[4] = {}, accv[4] = {};
#pragma unroll
        for (int kt = 0; kt < 2; kt++)
#pragma unroll
            for (int mt = 0; mt < 4; mt++) {
                accq[mt] = __builtin_amdgcn_mfma_f32_16x16x32_bf16(aq[kt][mt], b[kt], accq[mt], 0, 0, 0);
                acck[mt] = __builtin_amdgcn_mfma_f32_16x16x32_bf16(ak[kt][mt], b[kt], acck[mt], 0, 0, 0);
                accv[mt] = __builtin_amdgcn_mfma_f32_16x16x32_bf16(av[kt][mt], b[kt], accv[mt], 0, 0, 0);
            }
        // Q: direct fp32 stores (4 quads cover a full 64B line per (node,mt))
#pragma unroll
        for (int mt = 0; mt < 4; mt++)
            *(float4*)(Qh + (size_t)(e0 + ml) * D + mt*16 + quad*4) =
                make_float4(accq[mt][0], accq[mt][1], accq[mt][2], accq[mt][3]);
        // K then V: bf16 LDS staging, coalesced 128B-row stores
        const int el = lane >> 2, c = lane & 3;
#pragma unroll
        for (int mt = 0; mt < 4; mt++)
            *(ushort4*)&st[w][ml*72 + mt*16 + quad*4] =
                make_ushort4(f2bf(acck[mt][0]), f2bf(acck[mt][1]),
                             f2bf(acck[mt][2]), f2bf(acck[mt][3]));
        {
            uint4 r0 = *(const uint4*)&st[w][el*72 + c*16 + 0];
            uint4 r1 = *(const uint4*)&st[w][el*72 + c*16 + 8];
            uint4* gp = (uint4*)(Kb + (size_t)(e0 + el) * D + c*16);
            gp[0] = r0; gp[1] = r1;
        }
#pragma unroll
        for (int mt = 0; mt < 4; mt++)
            *(ushort4*)&st[w][ml*72 + mt*16 + quad*4] =
                make_ushort4(f2bf(accv[mt][0]), f2bf(accv[mt][1]),
                             f2bf(accv[mt][2]), f2bf(accv[mt][3]));
        {
            uint4 r0 = *(const uint4*)&st[w][el*72 + c*16 + 0];
            uint4 r1 = *(const uint4*)&st[w][el*72 + c*16 + 8];
            uint4* gp = (uint4*)(Vb + (size_t)(e0 + el) * D + c*16);
            gp[0] = r0; gp[1] = r1;
        }
    }
}

// Eh = edge_attr @ WE via MFMA, rows written in CSR order (eperm scatter).
__global__ __launch_bounds__(256) void k_eh_mfma(const float* __restrict__ ea,
        const unsigned short* __restrict__ weT, const int* __restrict__ eperm,
        unsigned short* __restrict__ Eh) {
    __shared__ unsigned short st[4][16 * 72];
    const int lane = threadIdx.x & 63;
    const int w    = threadIdx.x >> 6;
    const int ml   = lane & 15;
    const int quad = lane >> 4;

    bf16x8 afr[2][4];
#pragma unroll
    for (int kt = 0; kt < 2; kt++)
#pragma unroll
        for (int mt = 0; mt < 4; mt++)
            afr[kt][mt] = *(const bf16x8*)&weT[(mt*16 + ml)*64 + kt*32 + quad*8];

    const int wave = blockIdx.x * 4 + w;
    const int nw   = gridDim.x * 4;
    for (int tile = wave; tile < NE / 16; tile += nw) {
        const int e0 = tile * 16;
        const float4* ar = (const float4*)(ea + (size_t)(e0 + ml) * D);
        floatx4 acc[4] = {};
#pragma unroll
        for (int kt = 0; kt < 2; kt++) {
            float4 f0 = ar[kt*8 + quad*2 + 0];
            float4 f1 = ar[kt*8 + quad*2 + 1];
            bf16x8 b;
            b[0] = (__bf16)f0.x; b[1] = (__bf16)f0.y; b[2] = (__bf16)f0.z; b[3] = (__bf16)f0.w;
            b[4] = (__bf16)f1.x; b[5] = (__bf16)f1.y; b[6] = (__bf16)f1.z; b[7] = (__bf16)f1.w;
#pragma unroll
            for (int mt = 0; mt < 4; mt++)
                acc[mt] = __builtin_amdgcn_mfma_f32_16x16x32_bf16(afr[kt][mt], b, acc[mt], 0, 0, 0);
        }
#pragma unroll
        for (int mt = 0; mt < 4; mt++)
            *(ushort4*)&st[w][ml*72 + mt*16 + quad*4] =
                make_ushort4(f2bf(acc[mt][0]), f2bf(acc[mt][1]),
                             f2bf(acc[mt][2]), f2bf(acc[mt][3]));
        const int el = lane >> 2, c = lane & 3;
        int pos = eperm[e0 + el];
        uint4 r0 = *(const uint4*)&st[w][el*72 + c*16 + 0];
        uint4 r1 = *(const uint4*)&st[w][el*72 + c*16 + 8];
        uint4* gp = (uint4*)(Eh + (size_t)pos * D + c*16);
        gp[0] = r0;
        gp[1] = r1;
    }
}

// node-parallel attention aggregation: 16 lanes per node, no float atomics.
// Eh is in CSR order -> sequential stream; K/V are bf16 gathers (128B rows).
__global__ __launch_bounds__(256) void k_agg(const float* __restrict__ Qh,
        const unsigned short* __restrict__ Kb, const unsigned short* __restrict__ Vb,
        const unsigned short* __restrict__ Eh,
        const int* __restrict__ row_off, const int* __restrict__ csr_src,
        float* __restrict__ h_attn) {
    int t = blockIdx.x * 256 + threadIdx.x;
    int node = t >> 4;
    int lane = t & 15;
    if (node >= NN) return;
    int beg = row_off[node], end = row_off[node + 1];
    float4 q = ((const float4*)(Qh + (size_t)node * D))[lane];
    float4 acc = make_float4(0.f, 0.f, 0.f, 0.f);
    float z = 0.f;
    for (int i = beg; i < end; i++) {
        int s = csr_src[i];
        ushort4 kb = *(const ushort4*)(Kb + (size_t)s * D + lane * 4);
        ushort4 eb = *(const ushort4*)(Eh + (size_t)i * D + lane * 4);
        float part = bf2f(kb.x) * q.x * bf2f(eb.x) + bf2f(kb.y) * q.y * bf2f(eb.y)
                   + bf2f(kb.z) * q.z * bf2f(eb.z) + bf2f(kb.w) * q.w * bf2f(eb.w);
        part += __shfl_xor(part, 1, 64);
        part += __shfl_xor(part, 2, 64);       // sum over the head's 16 dims
        float sv = part * 0.25f;               // / sqrt(DH)
        sv = fminf(5.f, fmaxf(-5.f, sv));
        float sc = __expf(sv);
        ushort4 vb = *(const ushort4*)(Vb + (size_t)s * D + lane * 4);
        acc.x += sc * bf2f(vb.x); acc.y += sc * bf2f(vb.y);
        acc.z += sc * bf2f(vb.z); acc.w += sc * bf2f(vb.w);
        z += sc;
    }
    float inv = 1.f / (z + 1e-6f);
    ((float4*)(h_attn + (size_t)node * D))[lane] =
        make_float4(acc.x * inv, acc.y * inv, acc.z * inv, acc.w * inv);
}

// MFMA-based fused post block: one 16-node tile per wave.
__global__ __launch_bounds__(512) void k_post_mfma(const float* __restrict__ h_in,
        const float* __restrict__ h_attn,
        const unsigned short* __restrict__ woT_g,
        const unsigned short* __restrict__ w1T_g,
        const unsigned short* __restrict__ w2T_g,
        const float* __restrict__ bo,
        const float* __restrict__ g1, const float* __restrict__ be1,
        const float* __restrict__ b1, const float* __restrict__ b2,
        const float* __restrict__ g2, const float* __restrict__ be2,
        float* __restrict__ h_out) {
    __shared__ unsigned short woT_s[64 * 72];
    __shared__ unsigned short w1T_s[128 * 72];
    __shared__ unsigned short w2T_s[64 * 136];
    __shared__ unsigned short stg[8][16 * 136];

    const int t = threadIdx.x;
    {
        const uint4* s0 = (const uint4*)woT_g;
        { int i = t; if (i < 512) { int row = i >> 3, c = i & 7;
              *(uint4*)&woT_s[row*72 + c*8] = s0[i]; } }
        const uint4* s1 = (const uint4*)w1T_g;
        for (int i = t; i < 1024; i += 512) {
            int row = i >> 3, c = i & 7;
            *(uint4*)&w1T_s[row*72 + c*8] = s1[i];
        }
        const uint4* s2 = (const uint4*)w2T_g;
        for (int i = t; i < 1024; i += 512) {
            int row = i >> 4, c = i & 15;
            *(uint4*)&w2T_s[row*136 + c*8] = s2[i];
        }
    }
    __syncthreads();

    const int w = t >> 6, lane = t & 63;
    const int ml = lane & 15, quad = lane >> 4;
    const int tile = blockIdx.x * 8 + w;
    if (tile >= NN / 16) return;
    const int e0 = tile * 16;
    unsigned short* st = stg[w];

    // ---- GEMM1: tt = h_attn @ WO
    const float4* ap = (const float4*)(h_attn + (size_t)(e0 + ml) * D);
    floatx4 acc1[4] = {};
#pragma unroll
    for (int kt = 0; kt < 2; kt++) {
        float4 f0 = ap[kt*8 + quad*2 + 0];
        float4 f1 = ap[kt*8 + quad*2 + 1];
        bf16x8 b;
        b[0] = (__bf16)f0.x; b[1] = (__bf16)f0.y; b[2] = (__bf16)f0.z; b[3] = (__bf16)f0.w;
        b[4] = (__bf16)f1.x; b[5] = (__bf16)f1.y; b[6] = (__bf16)f1.z; b[7] = (__bf16)f1.w;
#pragma unroll
        for (int mt = 0; mt < 4; mt++) {
            bf16x8 a = *(const bf16x8*)&woT_s[(mt*16 + ml)*72 + kt*32 + quad*8];
            acc1[mt] = __builtin_amdgcn_mfma_f32_16x16x32_bf16(a, b, acc1[mt], 0, 0, 0);
        }
    }
    const float4* hp  = (const float4*)(h_in + (size_t)(e0 + ml) * D);
    const float4* bo4 = (const float4*)bo;
    floatx4 tt[4];
#pragma unroll
    for (int mt = 0; mt < 4; mt++) {
        float4 hh = hp[mt*4 + quad];
        float4 bb = bo4[mt*4 + quad];
        tt[mt][0] = acc1[mt][0] + hh.x + bb.x;
        tt[mt][1] = acc1[mt][1] + hh.y + bb.y;
        tt[mt][2] = acc1[mt][2] + hh.z + bb.z;
        tt[mt][3] = acc1[mt][3] + hh.w + bb.w;
    }
    float s = 0.f;
#pragma unroll
    for (int mt = 0; mt < 4; mt++) s += tt[mt][0] + tt[mt][1] + tt[mt][2] + tt[mt][3];
    s += __shfl_xor(s, 16, 64); s += __shfl_xor(s, 32, 64);
    float mu = s * (1.f / 64.f);
    float v = 0.f;
#pragma unroll
    for (int mt = 0; mt < 4; mt++)
#pragma unroll
        for (int r = 0; r < 4; r++) { float c = tt[mt][r] - mu; v += c * c; }
    v += __shfl_xor(v, 16, 64); v += __shfl_xor(v, 32, 64);
    float rstd = rsqrtf(v * (1.f / 64.f) + 1e-5f);
    const float4* g1v  = (const float4*)g1;
    const float4* be1v = (const float4*)be1;
    floatx4 h1[4];
#pragma unroll
    for (int mt = 0; mt < 4; mt++) {
        float4 gg = g1v[mt*4 + quad];
        float4 bb = be1v[mt*4 + quad];
        h1[mt][0] = (tt[mt][0] - mu) * rstd * gg.x + bb.x;
        h1[mt][1] = (tt[mt][1] - mu) * rstd * gg.y + bb.y;
        h1[mt][2] = (tt[mt][2] - mu) * rstd * gg.z + bb.z;
        h1[mt][3] = (tt[mt][3] - mu) * rstd * gg.w + bb.w;
        *(ushort4*)&st[ml*136 + mt*16 + quad*4] =
            make_ushort4(f2bf(h1[mt][0]), f2bf(h1[mt][1]), f2bf(h1[mt][2]), f2bf(h1[mt][3]));
    }

    // ---- GEMM2: y = relu(h1 @ W1 + b1)
    bf16x8 bh[2];
#pragma unroll
    for (int kt = 0; kt < 2; kt++)
        bh[kt] = *(const bf16x8*)&st[ml*136 + kt*32 + quad*8];
    floatx4 acc2[8] = {};
#pragma unroll
    for (int kt = 0; kt < 2; kt++)
#pragma unroll
        for (int mt = 0; mt < 8; mt++) {
            bf16x8 a = *(const bf16x8*)&w1T_s[(mt*16 + ml)*72 + kt*32 + quad*8];
            acc2[mt] = __builtin_amdgcn_mfma_f32_16x16x32_bf16(a, bh[kt], acc2[mt], 0, 0, 0);
        }
    const float4* b1v = (const float4*)b1;
#pragma unroll
    for (int mt = 0; mt < 8; mt++) {
        float4 bb = b1v[mt*4 + quad];
        float y0 = fmaxf(acc2[mt][0] + bb.x, 0.f);
        float y1 = fmaxf(acc2[mt][1] + bb.y, 0.f);
        float y2 = fmaxf(acc2[mt][2] + bb.z, 0.f);
        float y3 = fmaxf(acc2[mt][3] + bb.w, 0.f);
        *(ushort4*)&st[ml*136 + mt*16 + quad*4] =
            make_ushort4(f2bf(y0), f2bf(y1), f2bf(y2), f2bf(y3));
    }

    // ---- GEMM3: z = y @ W2
    floatx4 acc3[4] = {};
#pragma unroll
    for (int kt = 0; kt < 4; kt++) {
        bf16x8 b = *(const bf16x8*)&st[ml*136 + kt*32 + quad*8];
#pragma unroll
        for (int mt = 0; mt < 4; mt++) {
            bf16x8 a = *(const bf16x8*)&w2T_s[(mt*16 + ml)*136 + kt*32 + quad*8];
            acc3[mt] = __builtin_amdgcn_mfma_f32_16x16x32_bf16(a, b, acc3[mt], 0, 0, 0);
        }
    }
    const float4* b2v = (const float4*)b2;
#pragma unroll
    for (int mt = 0; mt < 4; mt++) {
        float4 bb = b2v[mt*4 + quad];
        tt[mt][0] = acc3[mt][0] + bb.x + h1[mt][0];
        tt[mt][1] = acc3[mt][1] + bb.y + h1[mt][1];
        tt[mt][2] = acc3[mt][2] + bb.z + h1[mt][2];
        tt[mt][3] = acc3[mt][3] + bb.w + h1[mt][3];
    }
    s = 0.f;
#pragma unroll
    for (int mt = 0; mt < 4; mt++) s += tt[mt][0] + tt[mt][1] + tt[mt][2] + tt[mt][3];
    s += __shfl_xor(s, 16, 64); s += __shfl_xor(s, 32, 64);
    mu = s * (1.f / 64.f);
    v = 0.f;
#pragma unroll
    for (int mt = 0; mt < 4; mt++)
#pragma unroll
        for (int r = 0; r < 4; r++) { float c = tt[mt][r] - mu; v += c * c; }
    v += __shfl_xor(v, 16, 64); v += __shfl_xor(v, 32, 64);
    rstd = rsqrtf(v * (1.f / 64.f) + 1e-5f);
    const float4* g2v  = (const float4*)g2;
    const float4* be2v = (const float4*)be2;
    float4* outp = (float4*)(h_out + (size_t)(e0 + ml) * D);
#pragma unroll
    for (int mt = 0; mt < 4; mt++) {
        float4 gg = g2v[mt*4 + quad];
        float4 bb = be2v[mt*4 + quad];
        float4 o;
        o.x = (tt[mt][0] - mu) * rstd * gg.x + bb.x;
        o.y = (tt[mt][1] - mu) * rstd * gg.y + bb.y;
        o.z = (tt[mt][2] - mu) * rstd * gg.z + bb.z;
        o.w = (tt[mt][3] - mu) * rstd * gg.w + bb.w;
        outp[mt*4 + quad] = o;
    }
}

// ---------------- launch ----------------

extern "C" void kernel_launch(void* const* d_in, const int* in_sizes, int n_in,
                              void* d_out, int out_size, void* d_ws, size_t ws_size,
                              hipStream_t stream) {
    const float* x   = (const float*)d_in[0];
    const float* ea  = (const float*)d_in[1];
    const int*   ei  = (const int*)d_in[2];
    const float* WQ  = (const float*)d_in[3];
    const float* WK  = (const float*)d_in[4];
    const float* WE  = (const float*)d_in[5];
    const float* WV  = (const float*)d_in[6];
    const float* WO  = (const float*)d_in[7];
    const float* bO  = (const float*)d_in[8];
    const float* g1  = (const float*)d_in[9];
    const float* be1 = (const float*)d_in[10];
    const float* W1  = (const float*)d_in[11];
    const float* b1  = (const float*)d_in[12];
    const float* W2  = (const float*)d_in[13];
    const float* b2  = (const float*)d_in[14];
    const float* g2  = (const float*)d_in[15];
    const float* be2 = (const float*)d_in[16];
    float* out = (float*)d_out;

    char* wsb = (char*)d_ws;
    size_t off = 0;
    auto alloc = [&](size_t bytes) {
        void* p = wsb + off;
        off += (bytes + 255) & ~(size_t)255;
        return p;
    };
    float* Qh            = (float*)alloc((size_t)NN * D * 4);
    unsigned short* Kb   = (unsigned short*)alloc((size_t)NN * D * 2);
    unsigned short* Vb   = (unsigned short*)alloc((size_t)NN * D * 2);
    float* hbuf          = (float*)alloc((size_t)NN * D * 4);
    float* hattn         = (float*)alloc((size_t)NN * D * 4);
    unsigned short* Eh   = (unsigned short*)alloc((size_t)NE * D * 2);
    int* row_off         = (int*)alloc((size_t)(NN + 1) * 4);
    int* cursor          = (int*)alloc((size_t)NN * 4);
    int* deg             = (int*)alloc((size_t)NN * 4);
    int* csr_src         = (int*)alloc((size_t)NE * 4);
    int* eperm           = (int*)alloc((size_t)NE * 4);
    unsigned short* wqT  = (unsigned short*)alloc((size_t)2 * 4096 * 2);
    unsigned short* wkT  = (unsigned short*)alloc((size_t)2 * 4096 * 2);
    unsigned short* wvT  = (unsigned short*)alloc((size_t)2 * 4096 * 2);
    unsigned short* weT  = (unsigned short*)alloc((size_t)2 * 4096 * 2);
    unsigned short* woT  = (unsigned short*)alloc((size_t)2 * 4096 * 2);
    unsigned short* w1T  = (unsigned short*)alloc((size_t)2 * 8192 * 2);
    unsigned short* w2T  = (unsigned short*)alloc((size_t)2 * 8192 * 2);

    // CSR build + weight prep (once per call)
    hipMemsetAsync(deg, 0, (size_t)NN * 4, stream);
    k_deg<<<(NE + 255) / 256, 256, 0, stream>>>(ei, deg);
    k_scan<<<1, 1024, 0, stream>>>(deg, row_off, cursor);
    k_scatter<<<(NE + 255) / 256, 256, 0, stream>>>(ei, cursor, csr_src, eperm);
    k_prep<<<(2 * 36864 + 255) / 256, 256, 0, stream>>>(WQ, WK, WV, WE, WO, W1, W2,
            wqT, wkT, wvT, weT, woT, w1T, w2T);

    for (int l = 0; l < NL; l++) {
        const float* hcur = (l == 0) ? x : hbuf;
        float* hnxt = (l == NL - 1) ? out : hbuf;
        k_qkv_mfma<<<256, 256, 0, stream>>>(hcur, wqT + l * 4096, wkT + l * 4096,
                                            wvT + l * 4096, Qh, Kb, Vb);
        k_eh_mfma<<<1024, 256, 0, stream>>>(ea, weT + l * 4096, eperm, Eh);
        k_agg<<<(NN * 16 + 255) / 256, 256, 0, stream>>>(Qh, Kb, Vb, Eh, row_off, csr_src, hattn);
        k_post_mfma<<<(NN / 16 + 7) / 8, 512, 0, stream>>>(hcur, hattn,
                woT + l * 4096, w1T + l * 8192, w2T + l * 8192,
                bO + l * 64, g1 + l * 64, be1 + l * 64,
                b1 + l * 128, b2 + l * 64,
                g2 + l * 64, be2 + l * 64, hnxt);
    }
}

// Round 5
// 717.656 us; speedup vs baseline: 1.9279x; 1.0408x over previous
//
#include <hip/hip_runtime.h>

#define NN 50000
#define NE 800000
#define D  64
#define NL 2

typedef __bf16 bf16x8 __attribute__((ext_vector_type(8)));
typedef float  floatx4 __attribute__((ext_vector_type(4)));

static __device__ __forceinline__ float bf2f(unsigned short u) {
    return __uint_as_float(((unsigned)u) << 16);
}
static __device__ __forceinline__ unsigned short f2bf(float x) {
    unsigned u = __float_as_uint(x);
    u += 0x7fff + ((u >> 16) & 1);   // RNE
    return (unsigned short)(u >> 16);
}

// ---------------- CSR build (edge_index is identical for both layers) ----------------

__global__ void k_deg(const int* __restrict__ ei, int* __restrict__ deg) {
    int e = blockIdx.x * 256 + threadIdx.x;
    if (e < NE) atomicAdd(&deg[ei[NE + e]], 1);
}

__global__ void k_scan(const int* __restrict__ deg, int* __restrict__ row_off,
                       int* __restrict__ cursor) {
    __shared__ int buf[1024];
    __shared__ int carry_s;
    if (threadIdx.x == 0) carry_s = 0;
    __syncthreads();
    for (int base = 0; base < NN; base += 1024) {
        int i = base + (int)threadIdx.x;
        int v = (i < NN) ? deg[i] : 0;
        buf[threadIdx.x] = v;
        __syncthreads();
        for (int offt = 1; offt < 1024; offt <<= 1) {
            int t = (threadIdx.x >= (unsigned)offt) ? buf[threadIdx.x - offt] : 0;
            __syncthreads();
            buf[threadIdx.x] += t;
            __syncthreads();
        }
        int inc = buf[threadIdx.x] + carry_s;   // inclusive prefix through i
        if (i < NN) {
            row_off[i + 1] = inc;
            cursor[i] = inc - v;                 // exclusive
            if (i == 0) row_off[0] = 0;
        }
        __syncthreads();
        if (threadIdx.x == 1023) carry_s = inc;
        __syncthreads();
    }
}

// csr_src[pos] = src ; eperm[e] = pos  (Eh gets written in CSR order)
__global__ void k_scatter(const int* __restrict__ ei, int* __restrict__ cursor,
                          int* __restrict__ csr_src, int* __restrict__ eperm) {
    int e = blockIdx.x * 256 + threadIdx.x;
    if (e < NE) {
        int dst = ei[NE + e];
        int pos = atomicAdd(&cursor[dst], 1);
        csr_src[pos] = ei[e];
        eperm[e] = pos;
    }
}

// transpose all weights to bf16 m-major [m][k] once per call.
__global__ __launch_bounds__(256) void k_prep(
        const float* __restrict__ WQ, const float* __restrict__ WK,
        const float* __restrict__ WV, const float* __restrict__ WE,
        const float* __restrict__ WO, const float* __restrict__ W1,
        const float* __restrict__ W2,
        unsigned short* __restrict__ wqT, unsigned short* __restrict__ wkT,
        unsigned short* __restrict__ wvT, unsigned short* __restrict__ weT,
        unsigned short* __restrict__ woT, unsigned short* __restrict__ w1T,
        unsigned short* __restrict__ w2T) {
    int idx = blockIdx.x * 256 + threadIdx.x;
    if (idx >= 2 * 36864) return;
    int l = idx / 36864;
    int r = idx % 36864;
    if (r < 20480) {                       // five 64x64 matrices
        int which = r >> 12, rr = r & 4095;
        int m = rr >> 6, k = rr & 63;
        const float* src = (which == 0 ? WQ : which == 1 ? WK : which == 2 ? WV :
                            which == 3 ? WE : WO);
        unsigned short* dst = (which == 0 ? wqT : which == 1 ? wkT : which == 2 ? wvT :
                               which == 3 ? weT : woT);
        dst[l * 4096 + rr] = f2bf(src[l * 4096 + k * 64 + m]);
    } else if (r < 28672) {                // W1: [64k][128m] -> w1T[m][k]
        int r2 = r - 20480;
        int m = r2 >> 6, k = r2 & 63;
        w1T[l * 8192 + r2] = f2bf(W1[l * 8192 + k * 128 + m]);
    } else {                               // W2: [128k][64m] -> w2T[m][k]
        int r3 = r - 28672;
        int m = r3 >> 7, k = r3 & 127;
        w2T[l * 8192 + r3] = f2bf(W2[l * 8192 + k * 64 + m]);
    }
}

// ---------------- kernels ----------------

// QKV via MFMA: one 16-node tile per wave. Q fp32 direct stores, K/V bf16 via LDS.
__global__ __launch_bounds__(256) void k_qkv_mfma(const float* __restrict__ h,
        const unsigned short* __restrict__ wqT, const unsigned short* __restrict__ wkT,
        const unsigned short* __restrict__ wvT,
        float* __restrict__ Qh, unsigned short* __restrict__ Kb,
        unsigned short* __restrict__ Vb) {
    __shared__ unsigned short st[4][16 * 72];
    const int lane = threadIdx.x & 63;
    const int w    = threadIdx.x >> 6;
    const int ml   = lane & 15;
    const int quad = lane >> 4;

    bf16x8 aq[2][4], ak[2][4], av[2][4];
#pragma unroll
    for (int kt = 0; kt < 2; kt++)
#pragma unroll
        for (int mt = 0; mt < 4; mt++) {
            int o = (mt*16 + ml)*64 + kt*32 + quad*8;
            aq[kt][mt] = *(const bf16x8*)&wqT[o];
            ak[kt][mt] = *(const bf16x8*)&wkT[o];
            av[kt][mt] = *(const bf16x8*)&wvT[o];
        }

    const int wave = blockIdx.x * 4 + w;
    const int nw   = gridDim.x * 4;
    for (int tile = wave; tile < NN / 16; tile += nw) {
        const int e0 = tile * 16;
        const float4* ar = (const float4*)(h + (size_t)(e0 + ml) * D);
        bf16x8 b[2];
#pragma unroll
        for (int kt = 0; kt < 2; kt++) {
            float4 f0 = ar[kt*8 + quad*2 + 0];
            float4 f1 = ar[kt*8 + quad*2 + 1];
            b[kt][0] = (__bf16)f0.x; b[kt][1] = (__bf16)f0.y;
            b[kt][2] = (__bf16)f0.z; b[kt][3] = (__bf16)f0.w;
            b[kt][4] = (__bf16)f1.x; b[kt][5] = (__bf16)f1.y;
            b[kt][6] = (__bf16)f1.z; b[kt][7] = (__bf16)f1.w;
        }
        floatx4 accq[4] = {}, acck[4] = {}, accv[4] = {};
#pragma unroll
        for (int kt = 0; kt < 2; kt++)
#pragma unroll
            for (int mt = 0; mt < 4; mt++) {
                accq[mt] = __builtin_amdgcn_mfma_f32_16x16x32_bf16(aq[kt][mt], b[kt], accq[mt], 0, 0, 0);
                acck[mt] = __builtin_amdgcn_mfma_f32_16x16x32_bf16(ak[kt][mt], b[kt], acck[mt], 0, 0, 0);
                accv[mt] = __builtin_amdgcn_mfma_f32_16x16x32_bf16(av[kt][mt], b[kt], accv[mt], 0, 0, 0);
            }
#pragma unroll
        for (int mt = 0; mt < 4; mt++)
            *(float4*)(Qh + (size_t)(e0 + ml) * D + mt*16 + quad*4) =
                make_float4(accq[mt][0], accq[mt][1], accq[mt][2], accq[mt][3]);
        const int el = lane >> 2, c = lane & 3;
#pragma unroll
        for (int mt = 0; mt < 4; mt++)
            *(ushort4*)&st[w][ml*72 + mt*16 + quad*4] =
                make_ushort4(f2bf(acck[mt][0]), f2bf(acck[mt][1]),
                             f2bf(acck[mt][2]), f2bf(acck[mt][3]));
        {
            uint4 r0 = *(const uint4*)&st[w][el*72 + c*16 + 0];
            uint4 r1 = *(const uint4*)&st[w][el*72 + c*16 + 8];
            uint4* gp = (uint4*)(Kb + (size_t)(e0 + el) * D + c*16);
            gp[0] = r0; gp[1] = r1;
        }
#pragma unroll
        for (int mt = 0; mt < 4; mt++)
            *(ushort4*)&st[w][ml*72 + mt*16 + quad*4] =
                make_ushort4(f2bf(accv[mt][0]), f2bf(accv[mt][1]),
                             f2bf(accv[mt][2]), f2bf(accv[mt][3]));
        {
            uint4 r0 = *(const uint4*)&st[w][el*72 + c*16 + 0];
            uint4 r1 = *(const uint4*)&st[w][el*72 + c*16 + 8];
            uint4* gp = (uint4*)(Vb + (size_t)(e0 + el) * D + c*16);
            gp[0] = r0; gp[1] = r1;
        }
    }
}

// Eh for BOTH layers in one pass over edge_attr (B-fragments are layer-invariant).
// Rows written in CSR order (eperm scatter).
__global__ __launch_bounds__(256) void k_eh_mfma(const float* __restrict__ ea,
        const unsigned short* __restrict__ weT, const int* __restrict__ eperm,
        unsigned short* __restrict__ Eh) {
    __shared__ unsigned short st[4][16 * 72];
    const int lane = threadIdx.x & 63;
    const int w    = threadIdx.x >> 6;
    const int ml   = lane & 15;
    const int quad = lane >> 4;

    bf16x8 afr[2][2][4];   // [layer][kt][mt]
#pragma unroll
    for (int l = 0; l < 2; l++)
#pragma unroll
        for (int kt = 0; kt < 2; kt++)
#pragma unroll
            for (int mt = 0; mt < 4; mt++)
                afr[l][kt][mt] = *(const bf16x8*)&weT[l*4096 + (mt*16 + ml)*64 + kt*32 + quad*8];

    const int wave = blockIdx.x * 4 + w;
    const int nw   = gridDim.x * 4;
    const int el = lane >> 2, c = lane & 3;
    for (int tile = wave; tile < NE / 16; tile += nw) {
        const int e0 = tile * 16;
        const float4* ar = (const float4*)(ea + (size_t)(e0 + ml) * D);
        bf16x8 b[2];
#pragma unroll
        for (int kt = 0; kt < 2; kt++) {
            float4 f0 = ar[kt*8 + quad*2 + 0];
            float4 f1 = ar[kt*8 + quad*2 + 1];
            b[kt][0] = (__bf16)f0.x; b[kt][1] = (__bf16)f0.y;
            b[kt][2] = (__bf16)f0.z; b[kt][3] = (__bf16)f0.w;
            b[kt][4] = (__bf16)f1.x; b[kt][5] = (__bf16)f1.y;
            b[kt][6] = (__bf16)f1.z; b[kt][7] = (__bf16)f1.w;
        }
        int pos = eperm[e0 + el];
#pragma unroll
        for (int l = 0; l < 2; l++) {
            floatx4 acc[4] = {};
#pragma unroll
            for (int kt = 0; kt < 2; kt++)
#pragma unroll
                for (int mt = 0; mt < 4; mt++)
                    acc[mt] = __builtin_amdgcn_mfma_f32_16x16x32_bf16(afr[l][kt][mt], b[kt], acc[mt], 0, 0, 0);
#pragma unroll
            for (int mt = 0; mt < 4; mt++)
                *(ushort4*)&st[w][ml*72 + mt*16 + quad*4] =
                    make_ushort4(f2bf(acc[mt][0]), f2bf(acc[mt][1]),
                                 f2bf(acc[mt][2]), f2bf(acc[mt][3]));
            uint4 r0 = *(const uint4*)&st[w][el*72 + c*16 + 0];
            uint4 r1 = *(const uint4*)&st[w][el*72 + c*16 + 8];
            uint4* gp = (uint4*)(Eh + (size_t)l * NE * D + (size_t)pos * D + c*16);
            gp[0] = r0;
            gp[1] = r1;
        }
    }
}

// attention aggregation: ONE WAVE PER NODE. 4 edge-slots x 16 dim-lanes,
// unrolled x2 -> 8 edges / ~6 gathers in flight per iteration (latency fix).
__global__ __launch_bounds__(256) void k_agg(const float* __restrict__ Qh,
        const unsigned short* __restrict__ Kb, const unsigned short* __restrict__ Vb,
        const unsigned short* __restrict__ Eh,
        const int* __restrict__ row_off, const int* __restrict__ csr_src,
        float* __restrict__ h_attn) {
    const int node = blockIdx.x * 4 + (threadIdx.x >> 6);
    if (node >= NN) return;
    const int lane  = threadIdx.x & 63;
    const int eslot = lane >> 4;
    const int ml    = lane & 15;
    const int beg = row_off[node], end = row_off[node + 1];
    const float4 q = ((const float4*)(Qh + (size_t)node * D))[ml];
    float4 acc = make_float4(0.f, 0.f, 0.f, 0.f);
    float z = 0.f;

    int i0 = beg + eslot;
    while (i0 < end) {
        int i1 = i0 + 4;
        bool a1 = i1 < end;
        int s0 = csr_src[i0];
        int p1 = a1 ? i1 : i0;
        int s1 = a1 ? csr_src[p1] : s0;
        ushort4 kb0 = *(const ushort4*)(Kb + (size_t)s0 * D + ml * 4);
        ushort4 eb0 = *(const ushort4*)(Eh + (size_t)i0 * D + ml * 4);
        ushort4 vb0 = *(const ushort4*)(Vb + (size_t)s0 * D + ml * 4);
        ushort4 kb1 = *(const ushort4*)(Kb + (size_t)s1 * D + ml * 4);
        ushort4 eb1 = *(const ushort4*)(Eh + (size_t)p1 * D + ml * 4);
        ushort4 vb1 = *(const ushort4*)(Vb + (size_t)s1 * D + ml * 4);

        float part0 = bf2f(kb0.x) * q.x * bf2f(eb0.x) + bf2f(kb0.y) * q.y * bf2f(eb0.y)
                    + bf2f(kb0.z) * q.z * bf2f(eb0.z) + bf2f(kb0.w) * q.w * bf2f(eb0.w);
        float part1 = bf2f(kb1.x) * q.x * bf2f(eb1.x) + bf2f(kb1.y) * q.y * bf2f(eb1.y)
                    + bf2f(kb1.z) * q.z * bf2f(eb1.z) + bf2f(kb1.w) * q.w * bf2f(eb1.w);
        part0 += __shfl_xor(part0, 1, 64);
        part0 += __shfl_xor(part0, 2, 64);
        part1 += __shfl_xor(part1, 1, 64);
        part1 += __shfl_xor(part1, 2, 64);
        float sc0 = __expf(fminf(5.f, fmaxf(-5.f, part0 * 0.25f)));
        float sc1 = a1 ? __expf(fminf(5.f, fmaxf(-5.f, part1 * 0.25f))) : 0.f;

        acc.x += sc0 * bf2f(vb0.x) + sc1 * bf2f(vb1.x);
        acc.y += sc0 * bf2f(vb0.y) + sc1 * bf2f(vb1.y);
        acc.z += sc0 * bf2f(vb0.z) + sc1 * bf2f(vb1.z);
        acc.w += sc0 * bf2f(vb0.w) + sc1 * bf2f(vb1.w);
        z += sc0 + sc1;
        i0 += 8;
    }
    // merge the 4 edge-slots (butterfly over the eslot bits)
#pragma unroll
    for (int m = 16; m <= 32; m <<= 1) {
        acc.x += __shfl_xor(acc.x, m, 64);
        acc.y += __shfl_xor(acc.y, m, 64);
        acc.z += __shfl_xor(acc.z, m, 64);
        acc.w += __shfl_xor(acc.w, m, 64);
        z     += __shfl_xor(z, m, 64);
    }
    if (eslot == 0) {
        float inv = 1.f / (z + 1e-6f);
        ((float4*)(h_attn + (size_t)node * D))[ml] =
            make_float4(acc.x * inv, acc.y * inv, acc.z * inv, acc.w * inv);
    }
}

// MFMA-based fused post block: one 16-node tile per wave.
__global__ __launch_bounds__(512) void k_post_mfma(const float* __restrict__ h_in,
        const float* __restrict__ h_attn,
        const unsigned short* __restrict__ woT_g,
        const unsigned short* __restrict__ w1T_g,
        const unsigned short* __restrict__ w2T_g,
        const float* __restrict__ bo,
        const float* __restrict__ g1, const float* __restrict__ be1,
        const float* __restrict__ b1, const float* __restrict__ b2,
        const float* __restrict__ g2, const float* __restrict__ be2,
        float* __restrict__ h_out) {
    __shared__ unsigned short woT_s[64 * 72];
    __shared__ unsigned short w1T_s[128 * 72];
    __shared__ unsigned short w2T_s[64 * 136];
    __shared__ unsigned short stg[8][16 * 136];

    const int t = threadIdx.x;
    {
        const uint4* s0 = (const uint4*)woT_g;
        { int i = t; if (i < 512) { int row = i >> 3, c = i & 7;
              *(uint4*)&woT_s[row*72 + c*8] = s0[i]; } }
        const uint4* s1 = (const uint4*)w1T_g;
        for (int i = t; i < 1024; i += 512) {
            int row = i >> 3, c = i & 7;
            *(uint4*)&w1T_s[row*72 + c*8] = s1[i];
        }
        const uint4* s2 = (const uint4*)w2T_g;
        for (int i = t; i < 1024; i += 512) {
            int row = i >> 4, c = i & 15;
            *(uint4*)&w2T_s[row*136 + c*8] = s2[i];
        }
    }
    __syncthreads();

    const int w = t >> 6, lane = t & 63;
    const int ml = lane & 15, quad = lane >> 4;
    const int tile = blockIdx.x * 8 + w;
    if (tile >= NN / 16) return;
    const int e0 = tile * 16;
    unsigned short* st = stg[w];

    // ---- GEMM1: tt = h_attn @ WO
    const float4* ap = (const float4*)(h_attn + (size_t)(e0 + ml) * D);
    floatx4 acc1[4] = {};
#pragma unroll
    for (int kt = 0; kt < 2; kt++) {
        float4 f0 = ap[kt*8 + quad*2 + 0];
        float4 f1 = ap[kt*8 + quad*2 + 1];
        bf16x8 b;
        b[0] = (__bf16)f0.x; b[1] = (__bf16)f0.y; b[2] = (__bf16)f0.z; b[3] = (__bf16)f0.w;
        b[4] = (__bf16)f1.x; b[5] = (__bf16)f1.y; b[6] = (__bf16)f1.z; b[7] = (__bf16)f1.w;
#pragma unroll
        for (int mt = 0; mt < 4; mt++) {
            bf16x8 a = *(const bf16x8*)&woT_s[(mt*16 + ml)*72 + kt*32 + quad*8];
            acc1[mt] = __builtin_amdgcn_mfma_f32_16x16x32_bf16(a, b, acc1[mt], 0, 0, 0);
        }
    }
    const float4* hp  = (const float4*)(h_in + (size_t)(e0 + ml) * D);
    const float4* bo4 = (const float4*)bo;
    floatx4 tt[4];
#pragma unroll
    for (int mt = 0; mt < 4; mt++) {
        float4 hh = hp[mt*4 + quad];
        float4 bb = bo4[mt*4 + quad];
        tt[mt][0] = acc1[mt][0] + hh.x + bb.x;
        tt[mt][1] = acc1[mt][1] + hh.y + bb.y;
        tt[mt][2] = acc1[mt][2] + hh.z + bb.z;
        tt[mt][3] = acc1[mt][3] + hh.w + bb.w;
    }
    float s = 0.f;
#pragma unroll
    for (int mt = 0; mt < 4; mt++) s += tt[mt][0] + tt[mt][1] + tt[mt][2] + tt[mt][3];
    s += __shfl_xor(s, 16, 64); s += __shfl_xor(s, 32, 64);
    float mu = s * (1.f / 64.f);
    float v = 0.f;
#pragma unroll
    for (int mt = 0; mt < 4; mt++)
#pragma unroll
        for (int r = 0; r < 4; r++) { float c = tt[mt][r] - mu; v += c * c; }
    v += __shfl_xor(v, 16, 64); v += __shfl_xor(v, 32, 64);
    float rstd = rsqrtf(v * (1.f / 64.f) + 1e-5f);
    const float4* g1v  = (const float4*)g1;
    const float4* be1v = (const float4*)be1;
    floatx4 h1[4];
#pragma unroll
    for (int mt = 0; mt < 4; mt++) {
        float4 gg = g1v[mt*4 + quad];
        float4 bb = be1v[mt*4 + quad];
        h1[mt][0] = (tt[mt][0] - mu) * rstd * gg.x + bb.x;
        h1[mt][1] = (tt[mt][1] - mu) * rstd * gg.y + bb.y;
        h1[mt][2] = (tt[mt][2] - mu) * rstd * gg.z + bb.z;
        h1[mt][3] = (tt[mt][3] - mu) * rstd * gg.w + bb.w;
        *(ushort4*)&st[ml*136 + mt*16 + quad*4] =
            make_ushort4(f2bf(h1[mt][0]), f2bf(h1[mt][1]), f2bf(h1[mt][2]), f2bf(h1[mt][3]));
    }

    // ---- GEMM2: y = relu(h1 @ W1 + b1)
    bf16x8 bh[2];
#pragma unroll
    for (int kt = 0; kt < 2; kt++)
        bh[kt] = *(const bf16x8*)&st[ml*136 + kt*32 + quad*8];
    floatx4 acc2[8] = {};
#pragma unroll
    for (int kt = 0; kt < 2; kt++)
#pragma unroll
        for (int mt = 0; mt < 8; mt++) {
            bf16x8 a = *(const bf16x8*)&w1T_s[(mt*16 + ml)*72 + kt*32 + quad*8];
            acc2[mt] = __builtin_amdgcn_mfma_f32_16x16x32_bf16(a, bh[kt], acc2[mt], 0, 0, 0);
        }
    const float4* b1v = (const float4*)b1;
#pragma unroll
    for (int mt = 0; mt < 8; mt++) {
        float4 bb = b1v[mt*4 + quad];
        float y0 = fmaxf(acc2[mt][0] + bb.x, 0.f);
        float y1 = fmaxf(acc2[mt][1] + bb.y, 0.f);
        float y2 = fmaxf(acc2[mt][2] + bb.z, 0.f);
        float y3 = fmaxf(acc2[mt][3] + bb.w, 0.f);
        *(ushort4*)&st[ml*136 + mt*16 + quad*4] =
            make_ushort4(f2bf(y0), f2bf(y1), f2bf(y2), f2bf(y3));
    }

    // ---- GEMM3: z = y @ W2
    floatx4 acc3[4] = {};
#pragma unroll
    for (int kt = 0; kt < 4; kt++) {
        bf16x8 b = *(const bf16x8*)&st[ml*136 + kt*32 + quad*8];
#pragma unroll
        for (int mt = 0; mt < 4; mt++) {
            bf16x8 a = *(const bf16x8*)&w2T_s[(mt*16 + ml)*136 + kt*32 + quad*8];
            acc3[mt] = __builtin_amdgcn_mfma_f32_16x16x32_bf16(a, b, acc3[mt], 0, 0, 0);
        }
    }
    const float4* b2v = (const float4*)b2;
#pragma unroll
    for (int mt = 0; mt < 4; mt++) {
        float4 bb = b2v[mt*4 + quad];
        tt[mt][0] = acc3[mt][0] + bb.x + h1[mt][0];
        tt[mt][1] = acc3[mt][1] + bb.y + h1[mt][1];
        tt[mt][2] = acc3[mt][2] + bb.z + h1[mt][2];
        tt[mt][3] = acc3[mt][3] + bb.w + h1[mt][3];
    }
    s = 0.f;
#pragma unroll
    for (int mt = 0; mt < 4; mt++) s += tt[mt][0] + tt[mt][1] + tt[mt][2] + tt[mt][3];
    s += __shfl_xor(s, 16, 64); s += __shfl_xor(s, 32, 64);
    mu = s * (1.f / 64.f);
    v = 0.f;
#pragma unroll
    for (int mt = 0; mt < 4; mt++)
#pragma unroll
        for (int r = 0; r < 4; r++) { float c = tt[mt][r] - mu; v += c * c; }
    v += __shfl_xor(v, 16, 64); v += __shfl_xor(v, 32, 64);
    rstd = rsqrtf(v * (1.f / 64.f) + 1e-5f);
    const float4* g2v  = (const float4*)g2;
    const float4* be2v = (const float4*)be2;
    float4* outp = (float4*)(h_out + (size_t)(e0 + ml) * D);
#pragma unroll
    for (int mt = 0; mt < 4; mt++) {
        float4 gg = g2v[mt*4 + quad];
        float4 bb = be2v[mt*4 + quad];
        float4 o;
        o.x = (tt[mt][0] - mu) * rstd * gg.x + bb.x;
        o.y = (tt[mt][1] - mu) * rstd * gg.y + bb.y;
        o.z = (tt[mt][2] - mu) * rstd * gg.z + bb.z;
        o.w = (tt[mt][3] - mu) * rstd * gg.w + bb.w;
        outp[mt*4 + quad] = o;
    }
}

// ---------------- launch ----------------

extern "C" void kernel_launch(void* const* d_in, const int* in_sizes, int n_in,
                              void* d_out, int out_size, void* d_ws, size_t ws_size,
                              hipStream_t stream) {
    const float* x   = (const float*)d_in[0];
    const float* ea  = (const float*)d_in[1];
    const int*   ei  = (const int*)d_in[2];
    const float* WQ  = (const float*)d_in[3];
    const float* WK  = (const float*)d_in[4];
    const float* WE  = (const float*)d_in[5];
    const float* WV  = (const float*)d_in[6];
    const float* WO  = (const float*)d_in[7];
    const float* bO  = (const float*)d_in[8];
    const float* g1  = (const float*)d_in[9];
    const float* be1 = (const float*)d_in[10];
    const float* W1  = (const float*)d_in[11];
    const float* b1  = (const float*)d_in[12];
    const float* W2  = (const float*)d_in[13];
    const float* b2  = (const float*)d_in[14];
    const float* g2  = (const float*)d_in[15];
    const float* be2 = (const float*)d_in[16];
    float* out = (float*)d_out;

    char* wsb = (char*)d_ws;
    size_t off = 0;
    auto alloc = [&](size_t bytes) {
        void* p = wsb + off;
        off += (bytes + 255) & ~(size_t)255;
        return p;
    };
    float* Qh            = (float*)alloc((size_t)NN * D * 4);
    unsigned short* Kb   = (unsigned short*)alloc((size_t)NN * D * 2);
    unsigned short* Vb   = (unsigned short*)alloc((size_t)NN * D * 2);
    float* hbuf          = (float*)alloc((size_t)NN * D * 4);
    float* hattn         = (float*)alloc((size_t)NN * D * 4);
    unsigned short* Eh   = (unsigned short*)alloc((size_t)NL * NE * D * 2);
    int* row_off         = (int*)alloc((size_t)(NN + 1) * 4);
    int* cursor          = (int*)alloc((size_t)NN * 4);
    int* deg             = (int*)alloc((size_t)NN * 4);
    int* csr_src         = (int*)alloc((size_t)NE * 4);
    int* eperm           = (int*)alloc((size_t)NE * 4);
    unsigned short* wqT  = (unsigned short*)alloc((size_t)2 * 4096 * 2);
    unsigned short* wkT  = (unsigned short*)alloc((size_t)2 * 4096 * 2);
    unsigned short* wvT  = (unsigned short*)alloc((size_t)2 * 4096 * 2);
    unsigned short* weT  = (unsigned short*)alloc((size_t)2 * 4096 * 2);
    unsigned short* woT  = (unsigned short*)alloc((size_t)2 * 4096 * 2);
    unsigned short* w1T  = (unsigned short*)alloc((size_t)2 * 8192 * 2);
    unsigned short* w2T  = (unsigned short*)alloc((size_t)2 * 8192 * 2);

    // CSR build + weight prep (once per call)
    hipMemsetAsync(deg, 0, (size_t)NN * 4, stream);
    k_deg<<<(NE + 255) / 256, 256, 0, stream>>>(ei, deg);
    k_scan<<<1, 1024, 0, stream>>>(deg, row_off, cursor);
    k_scatter<<<(NE + 255) / 256, 256, 0, stream>>>(ei, cursor, csr_src, eperm);
    k_prep<<<(2 * 36864 + 255) / 256, 256, 0, stream>>>(WQ, WK, WV, WE, WO, W1, W2,
            wqT, wkT, wvT, weT, woT, w1T, w2T);
    // Eh for both layers in one pass over edge_attr
    k_eh_mfma<<<1024, 256, 0, stream>>>(ea, weT, eperm, Eh);

    for (int l = 0; l < NL; l++) {
        const float* hcur = (l == 0) ? x : hbuf;
        float* hnxt = (l == NL - 1) ? out : hbuf;
        k_qkv_mfma<<<782, 256, 0, stream>>>(hcur, wqT + l * 4096, wkT + l * 4096,
                                            wvT + l * 4096, Qh, Kb, Vb);
        k_agg<<<(NN + 3) / 4, 256, 0, stream>>>(Qh, Kb, Vb, Eh + (size_t)l * NE * D,
                                                row_off, csr_src, hattn);
        k_post_mfma<<<(NN / 16 + 7) / 8, 512, 0, stream>>>(hcur, hattn,
                woT + l * 4096, w1T + l * 8192, w2T + l * 8192,
                bO + l * 64, g1 + l * 64, be1 + l * 64,
                b1 + l * 128, b2 + l * 64,
                g2 + l * 64, be2 + l * 64, hnxt);
    }
}